// Round 8
// baseline (266.441 us; speedup 1.0000x reference)
//
#include <hip/hip_runtime.h>
#include <hip/hip_bf16.h>
#include <stdint.h>

#define D_DIM 2048
#define B_DIM 1024
#define N_TOT 3072
#define NCLS 64
#define NB128 (N_TOT / 128)   // 24 tiles per side
#define MARGIN_F 0.8f
#define BIG_F 1e30f

typedef float f32x4 __attribute__((ext_vector_type(4)));
typedef int   i32x4 __attribute__((ext_vector_type(4)));
typedef __bf16 bf16x8 __attribute__((ext_vector_type(8)));

// async global->LDS, 16B per lane (m97 staging pattern).
__device__ __forceinline__ void gld_lds16(const __bf16* g, __bf16* l) {
    __builtin_amdgcn_global_load_lds(
        (const __attribute__((address_space(1))) void*)g,
        (__attribute__((address_space(3))) void*)l,
        16, 0, 0);
}

__device__ __forceinline__ float rdlane(float v, int l) {
    return __int_as_float(__builtin_amdgcn_readlane(__float_as_int(v), l));
}

// ---------------- reduction helpers ----------------
__device__ inline float block_reduce_sum(float v, float* sred) {
    int tid = threadIdx.x;
    sred[tid] = v; __syncthreads();
    for (int s = 128; s > 0; s >>= 1) {
        if (tid < s) sred[tid] = sred[tid] + sred[tid + s];
        __syncthreads();
    }
    float r = sred[0]; __syncthreads();
    return r;
}
__device__ inline float block_sum4(float v, float* tmp4, int lane, int wave) {
    #pragma unroll
    for (int off = 32; off > 0; off >>= 1) v += __shfl_down(v, off);
    __syncthreads();
    if (lane == 0) tmp4[wave] = v;
    __syncthreads();
    return tmp4[0] + tmp4[1] + tmp4[2] + tmp4[3];
}
__device__ inline float wave_max(float v) {
    #pragma unroll
    for (int off = 32; off > 0; off >>= 1) v = fmaxf(v, __shfl_xor(v, off));
    return v;
}
__device__ inline float wave_min(float v) {
    #pragma unroll
    for (int off = 32; off > 0; off >>= 1) v = fminf(v, __shfl_xor(v, off));
    return v;
}

__device__ inline int label_of(int j, const int* __restrict__ albl, const int* __restrict__ nlbl) {
    return (j < 2 * B_DIM) ? albl[j & (B_DIM - 1)] : nlbl[j - 2 * B_DIM];
}

__device__ inline float sq8(f32x4 a, f32x4 b) {
    return a[0]*a[0] + a[1]*a[1] + a[2]*a[2] + a[3]*a[3]
         + b[0]*b[0] + b[1]*b[1] + b[2]*b[2] + b[3]*b[3];
}
__device__ inline void st_bf8(__bf16* dst, f32x4 v0, f32x4 v1) {
    bf16x8 o;
    o[0] = (__bf16)v0[0]; o[1] = (__bf16)v0[1]; o[2] = (__bf16)v0[2]; o[3] = (__bf16)v0[3];
    o[4] = (__bf16)v1[0]; o[5] = (__bf16)v1[1]; o[6] = (__bf16)v1[2]; o[7] = (__bf16)v1[3];
    *(bf16x8*)dst = o;
}

// ---------------- 0: zero accumulators + pack labels ----------------
__global__ __launch_bounds__(256) void zero_kernel(
        float* __restrict__ T, float* __restrict__ scal,
        const int* __restrict__ albl, const int* __restrict__ nlbl, int* __restrict__ lab) {
    int t = blockIdx.x * 256 + threadIdx.x;
    if (t < NCLS * NCLS) T[t] = 0.f;
    if (t < 8) scal[t] = 0.f;
    if (t < N_TOT) lab[t] = label_of(t, albl, nlbl);
}

// ---------------- 1: fused prep: bf16 convert + norms + exact triplet term ----------------
__global__ __launch_bounds__(256) void prep_kernel(
        const float* __restrict__ A, const float* __restrict__ P, const float* __restrict__ Ng,
        __bf16* __restrict__ Eb, float* __restrict__ norms, float* __restrict__ scal) {
    __shared__ float tmp4[4];
    int i = blockIdx.x, tid = threadIdx.x;
    int lane = tid & 63, wave = tid >> 6;
    const f32x4* a4 = (const f32x4*)(A + (size_t)i * D_DIM);
    const f32x4* p4 = (const f32x4*)(P + (size_t)i * D_DIM);
    const f32x4* n4 = (const f32x4*)(Ng + (size_t)i * D_DIM);
    f32x4 av0 = a4[tid * 2], av1 = a4[tid * 2 + 1];
    f32x4 pv0 = p4[tid * 2], pv1 = p4[tid * 2 + 1];
    f32x4 nv0 = n4[tid * 2], nv1 = n4[tid * 2 + 1];
    float sa = sq8(av0, av1), sp = sq8(pv0, pv1), sn = sq8(nv0, nv1);
    f32x4 dp0 = av0 - pv0, dp1 = av1 - pv1;
    f32x4 dn0 = av0 - nv0, dn1 = av1 - nv1;
    float pd = sq8(dp0, dp1), nd = sq8(dn0, dn1);
    st_bf8(Eb + (size_t)i * D_DIM + tid * 8, av0, av1);
    st_bf8(Eb + (size_t)(B_DIM + i) * D_DIM + tid * 8, pv0, pv1);
    st_bf8(Eb + (size_t)(2 * B_DIM + i) * D_DIM + tid * 8, nv0, nv1);
    float saT = block_sum4(sa, tmp4, lane, wave);
    float spT = block_sum4(sp, tmp4, lane, wave);
    float snT = block_sum4(sn, tmp4, lane, wave);
    float pdT = block_sum4(pd, tmp4, lane, wave);
    float ndT = block_sum4(nd, tmp4, lane, wave);
    if (tid == 0) {
        norms[i] = saT;
        norms[B_DIM + i] = spT;
        norms[2 * B_DIM + i] = snT;
        atomicAdd(&scal[0], fmaxf(pdT - ndT + MARGIN_F, 0.f));
    }
}

// ---------------- 2: bf16 MFMA Gram, upper triangle, global_load_lds staging (m97 structure) ----
__global__ __launch_bounds__(256) void gram_gemm(const __bf16* __restrict__ Eb, float* __restrict__ G) {
    __shared__ __bf16 As[128 * 32] __attribute__((aligned(16)));
    __shared__ __bf16 Bs[128 * 32] __attribute__((aligned(16)));
    int tid = threadIdx.x, lane = tid & 63, wave = tid >> 6;
    int by = 0, rem = blockIdx.x;
    while (rem >= NB128 - by) { rem -= (NB128 - by); ++by; }
    int bx = by + rem;
    size_t row0 = (size_t)by * 128, col0 = (size_t)bx * 128;
    int wr = wave >> 1, wc = wave & 1;
    f32x4 acc[4][4];
    #pragma unroll
    for (int m = 0; m < 4; ++m)
        #pragma unroll
        for (int n = 0; n < 4; ++n) acc[m][n] = (f32x4){0.f, 0.f, 0.f, 0.f};

    int rl = lane & 15;
    int kg = (lane >> 4) * 8;
    int srow = lane >> 2, scol = (lane & 3) * 8;
    const __bf16* gA0 = Eb + (row0 + wave * 32 + srow) * D_DIM + scol;
    const __bf16* gA1 = gA0 + 16 * D_DIM;
    const __bf16* gB0 = Eb + (col0 + wave * 32 + srow) * D_DIM + scol;
    const __bf16* gB1 = gB0 + 16 * D_DIM;
    __bf16* lA0 = &As[(wave * 32) * 32];
    __bf16* lA1 = &As[(wave * 32 + 16) * 32];
    __bf16* lB0 = &Bs[(wave * 32) * 32];
    __bf16* lB1 = &Bs[(wave * 32 + 16) * 32];

    for (int k0 = 0; k0 < D_DIM; k0 += 32) {
        __syncthreads();
        gld_lds16(gA0 + k0, lA0);
        gld_lds16(gA1 + k0, lA1);
        gld_lds16(gB0 + k0, lB0);
        gld_lds16(gB1 + k0, lB1);
        __syncthreads();
        bf16x8 af[4], bf[4];
        #pragma unroll
        for (int m = 0; m < 4; ++m)
            af[m] = *(const bf16x8*)&As[(wr * 64 + m * 16 + rl) * 32 + kg];
        #pragma unroll
        for (int n = 0; n < 4; ++n)
            bf[n] = *(const bf16x8*)&Bs[(wc * 64 + n * 16 + rl) * 32 + kg];
        #pragma unroll
        for (int m = 0; m < 4; ++m)
            #pragma unroll
            for (int n = 0; n < 4; ++n)
                acc[m][n] = __builtin_amdgcn_mfma_f32_16x16x32_bf16(af[m], bf[n], acc[m][n], 0, 0, 0);
    }
    int rg = (lane >> 4) * 4;
    #pragma unroll
    for (int m = 0; m < 4; ++m)
        #pragma unroll
        for (int n = 0; n < 4; ++n)
            #pragma unroll
            for (int r = 0; r < 4; ++r) {
                size_t row = row0 + wr * 64 + m * 16 + rg + r;
                size_t col = col0 + wc * 64 + n * 16 + rl;
                G[row * N_TOT + col] = acc[m][n][r];
            }
}

// ---------------- 3: mirror upper triangle into lower (64x64 LDS transpose tiles) ----------------
__global__ __launch_bounds__(256) void mirror_kernel(float* __restrict__ G) {
    __shared__ float s[64 * 65];
    int b = blockIdx.x;
    int p = b >> 2, q = b & 3;
    int bj = 0, rem = p;
    while (rem >= NB128 - 1 - bj) { rem -= (NB128 - 1 - bj); ++bj; }
    int bi = bj + 1 + rem;
    int ti = bi * 2 + (q >> 1), tj = bj * 2 + (q & 1);
    int tid = threadIdx.x;
    int c = tid & 63, r4 = tid >> 6;
    const float* src = G + ((size_t)tj * 64) * N_TOT + (size_t)ti * 64;
    float* dst = G + ((size_t)ti * 64) * N_TOT + (size_t)tj * 64;
    #pragma unroll
    for (int rr = 0; rr < 16; ++rr) {
        int row = rr * 4 + r4;
        s[row * 65 + c] = src[(size_t)row * N_TOT + c];
    }
    __syncthreads();
    #pragma unroll
    for (int rr = 0; rr < 16; ++rr) {
        int row = rr * 4 + r4;
        dst[(size_t)row * N_TOT + c] = s[c * 65 + row];
    }
}

// ---------------- 4: vectorized T-binning, rows B..N, per-wave bins (contention fix) ----------
__global__ __launch_bounds__(512) void tsumv_kernel(
        const float* __restrict__ G, const float* __restrict__ norms,
        const int* __restrict__ lab, float* __restrict__ T) {
    __shared__ float tlw[8 * 2 * NCLS];   // [wave][row][cls]
    int tid = threadIdx.x, wave = tid >> 6;
    int r0 = B_DIM + blockIdx.x * 2;
    tlw[tid] = 0.f;
    if (tid < 512) tlw[512 + tid] = 0.f;
    __syncthreads();
    #pragma unroll
    for (int rr = 0; rr < 2; ++rr) {
        int r = r0 + rr;
        float nr = norms[r];
        const float* Grow = G + (size_t)r * N_TOT;
        float* bins = &tlw[(wave * 2 + rr) * NCLS];
        #pragma unroll
        for (int it = 0; it < 2; ++it) {
            int jv = tid + it * 512;
            if (jv * 4 < N_TOT) {
                int j = jv * 4;
                f32x4 g = *(const f32x4*)&Grow[j];
                f32x4 nj = *(const f32x4*)&norms[j];
                i32x4 lj = *(const i32x4*)&lab[j];
                f32x4 d2 = nr + nj - 2.f * g;
                atomicAdd(&bins[lj[0]], sqrtf(fmaxf(d2[0], 1e-8f)));
                atomicAdd(&bins[lj[1]], sqrtf(fmaxf(d2[1], 1e-8f)));
                atomicAdd(&bins[lj[2]], sqrtf(fmaxf(d2[2], 1e-8f)));
                atomicAdd(&bins[lj[3]], sqrtf(fmaxf(d2[3], 1e-8f)));
            }
        }
    }
    __syncthreads();
    if (tid < 2 * NCLS) {
        int rr = tid >> 6, c = tid & 63;
        float s = 0.f;
        #pragma unroll
        for (int w = 0; w < 8; ++w) s += tlw[(w * 2 + rr) * NCLS + c];
        if (s != 0.f) atomicAdd(&T[lab[r0 + rr] * NCLS + c], s);
    }
}

// ---------------- 5: mining + successor + anchor-row T-binning, register-resident ----------
// R7 diagnosis: LDS-pipe bound (2048 same-address atomics + 768 ds_write_b128 + 768
// ds_read_b128 per block; ~40us/CU of LDS serialization). Now: dneg lives in REGISTERS
// (two f32x4/thread); successor scan = v_readlane broadcast over the wave's 512
// register elements (VALU, parallel across SIMDs); per-wave T-bins (4-way contention);
// shuffle hp/hn reductions. ~5 barriers total, ~5KB LDS.
__global__ __launch_bounds__(512) void minev_kernel(
        const float* __restrict__ G, const float* __restrict__ norms,
        const int* __restrict__ lab, float* __restrict__ T, float* __restrict__ scal) {
    __shared__ float tlw[8 * NCLS];      // per-wave T bins
    __shared__ float qlist[128];
    __shared__ float cpart[8 * 64];
    __shared__ float hpw[8], hnw[8];
    __shared__ int pcount;
    int i = blockIdx.x, tid = threadIdx.x;
    int lane = tid & 63, wave = tid >> 6;
    if (tid == 0) pcount = 0;
    tlw[tid] = 0.f;                      // 512 threads cover 8*64 exactly
    __syncthreads();
    int la = lab[i];
    float ni = norms[i];
    const float* Grow = G + (size_t)i * N_TOT;
    float hp = -BIG_F, hn = BIG_F;
    float* bins = &tlw[wave * NCLS];

    // ---- phase 1: two f32x4 element groups, dn values stay in registers ----
    f32x4 dnA, dnB;
    {   // group A: elements j = tid*4 .. +4  (covers 0..2047)
        int j = tid * 4;
        f32x4 g = *(const f32x4*)&Grow[j];
        f32x4 nj = *(const f32x4*)&norms[j];
        i32x4 lj = *(const i32x4*)&lab[j];
        f32x4 d2 = ni + nj - 2.f * g;
        float d0 = sqrtf(fmaxf(d2[0], 1e-8f));
        float d1 = sqrtf(fmaxf(d2[1], 1e-8f));
        float dd2 = sqrtf(fmaxf(d2[2], 1e-8f));
        float d3 = sqrtf(fmaxf(d2[3], 1e-8f));
        atomicAdd(&bins[lj[0]], d0);
        atomicAdd(&bins[lj[1]], d1);
        atomicAdd(&bins[lj[2]], dd2);
        atomicAdd(&bins[lj[3]], d3);
        bool n0 = lj[0] != la, n1 = lj[1] != la, n2 = lj[2] != la, n3 = lj[3] != la;
        dnA = (f32x4){ n0 ? d0 : BIG_F, n1 ? d1 : BIG_F, n2 ? dd2 : BIG_F, n3 ? d3 : BIG_F };
        hn = fminf(hn, fminf(fminf(dnA[0], dnA[1]), fminf(dnA[2], dnA[3])));
        if (!n0 && j + 0 != i) { hp = fmaxf(hp, d0); int p = atomicAdd(&pcount, 1); if (p < 128) qlist[p] = d0; }
        if (!n1 && j + 1 != i) { hp = fmaxf(hp, d1); int p = atomicAdd(&pcount, 1); if (p < 128) qlist[p] = d1; }
        if (!n2 && j + 2 != i) { hp = fmaxf(hp, dd2); int p = atomicAdd(&pcount, 1); if (p < 128) qlist[p] = dd2; }
        if (!n3 && j + 3 != i) { hp = fmaxf(hp, d3); int p = atomicAdd(&pcount, 1); if (p < 128) qlist[p] = d3; }
    }
    if (tid < 256) {   // group B: elements j = 2048 + tid*4 (covers 2048..3071)
        int j = 2048 + tid * 4;
        f32x4 g = *(const f32x4*)&Grow[j];
        f32x4 nj = *(const f32x4*)&norms[j];
        i32x4 lj = *(const i32x4*)&lab[j];
        f32x4 d2 = ni + nj - 2.f * g;
        float d0 = sqrtf(fmaxf(d2[0], 1e-8f));
        float d1 = sqrtf(fmaxf(d2[1], 1e-8f));
        float dd2 = sqrtf(fmaxf(d2[2], 1e-8f));
        float d3 = sqrtf(fmaxf(d2[3], 1e-8f));
        atomicAdd(&bins[lj[0]], d0);
        atomicAdd(&bins[lj[1]], d1);
        atomicAdd(&bins[lj[2]], dd2);
        atomicAdd(&bins[lj[3]], d3);
        bool n0 = lj[0] != la, n1 = lj[1] != la, n2 = lj[2] != la, n3 = lj[3] != la;
        dnB = (f32x4){ n0 ? d0 : BIG_F, n1 ? d1 : BIG_F, n2 ? dd2 : BIG_F, n3 ? d3 : BIG_F };
        hn = fminf(hn, fminf(fminf(dnB[0], dnB[1]), fminf(dnB[2], dnB[3])));
        if (!n0 && j + 0 != i) { hp = fmaxf(hp, d0); int p = atomicAdd(&pcount, 1); if (p < 128) qlist[p] = d0; }
        if (!n1 && j + 1 != i) { hp = fmaxf(hp, d1); int p = atomicAdd(&pcount, 1); if (p < 128) qlist[p] = d1; }
        if (!n2 && j + 2 != i) { hp = fmaxf(hp, dd2); int p = atomicAdd(&pcount, 1); if (p < 128) qlist[p] = dd2; }
        if (!n3 && j + 3 != i) { hp = fmaxf(hp, d3); int p = atomicAdd(&pcount, 1); if (p < 128) qlist[p] = d3; }
    } else {
        dnB = (f32x4){BIG_F, BIG_F, BIG_F, BIG_F};
    }
    float hpw_ = wave_max(hp), hnw_ = wave_min(hn);
    if (lane == 0) { hpw[wave] = hpw_; hnw[wave] = hnw_; }
    __syncthreads();                     // publishes bins, qlist, pcount, hpw/hnw

    // T-bin flush (row label fixed)
    if (tid < NCLS) {
        float s = 0.f;
        #pragma unroll
        for (int w = 0; w < 8; ++w) s += tlw[w * NCLS + tid];
        if (s != 0.f) atomicAdd(&T[la * NCLS + tid], s);
    }

    int P = min(pcount, 128);
    float shS = 0.f, shN = 0.f;          // accumulated in wave0 registers
    for (int q0 = 0; q0 < P; q0 += 64) {
        int nq = min(64, P - q0);
        float q = (lane < nq) ? qlist[q0 + lane] : BIG_F;
        // readlane broadcast scan over this wave's 512 register elements
        float c0 = BIG_F, c1 = BIG_F, c2 = BIG_F, c3 = BIG_F;
        #pragma unroll
        for (int l = 0; l < 64; ++l) {
            float a0 = rdlane(dnA[0], l), a1 = rdlane(dnA[1], l);
            float a2 = rdlane(dnA[2], l), a3 = rdlane(dnA[3], l);
            c0 = fminf(c0, (a0 > q) ? a0 : BIG_F);
            c1 = fminf(c1, (a1 > q) ? a1 : BIG_F);
            c2 = fminf(c2, (a2 > q) ? a2 : BIG_F);
            c3 = fminf(c3, (a3 > q) ? a3 : BIG_F);
            float b0 = rdlane(dnB[0], l), b1 = rdlane(dnB[1], l);
            float b2 = rdlane(dnB[2], l), b3 = rdlane(dnB[3], l);
            c0 = fminf(c0, (b0 > q) ? b0 : BIG_F);
            c1 = fminf(c1, (b1 > q) ? b1 : BIG_F);
            c2 = fminf(c2, (b2 > q) ? b2 : BIG_F);
            c3 = fminf(c3, (b3 > q) ? b3 : BIG_F);
        }
        cpart[wave * 64 + lane] = fminf(fminf(c0, c1), fminf(c2, c3));
        __syncthreads();
        if (wave == 0) {
            float cc = cpart[lane];
            #pragma unroll
            for (int w = 1; w < 8; ++w) cc = fminf(cc, cpart[w * 64 + lane]);
            float s = 0.f, n = 0.f;
            if (lane < nq && cc < 1e29f) {
                float qq = qlist[q0 + lane];
                if (cc < qq + MARGIN_F) { s = qq - cc + MARGIN_F; n = 1.f; }
            }
            #pragma unroll
            for (int off = 32; off > 0; off >>= 1) {
                s += __shfl_down(s, off);
                n += __shfl_down(n, off);
            }
            shS += s; shN += n;
        }
        __syncthreads();
    }
    if (wave == 0 && lane == 0) {
        float hpAll = hpw[0], hnAll = hnw[0];
        #pragma unroll
        for (int w = 1; w < 8; ++w) { hpAll = fmaxf(hpAll, hpw[w]); hnAll = fminf(hnAll, hnw[w]); }
        if (P > 0 && hnAll < 1e29f) {
            atomicAdd(&scal[1], fmaxf(hpAll - hnAll + MARGIN_F, 0.f));
            atomicAdd(&scal[2], 1.f);
        }
        if (shS != 0.f || shN != 0.f) {
            atomicAdd(&scal[3], shS);
            atomicAdd(&scal[4], shN);
        }
    }
}

// ---------------- 6: finalize: counts, intra/inter, combine ----------------
__global__ __launch_bounds__(256) void finalize_kernel(
        const float* __restrict__ T, const int* __restrict__ albl, const int* __restrict__ nlbl,
        const float* __restrict__ scal, float* __restrict__ out) {
    __shared__ int counts[NCLS];
    __shared__ int inA[NCLS];
    __shared__ float sred[256];
    int tid = threadIdx.x;
    if (tid < NCLS) { counts[tid] = 0; inA[tid] = 0; }
    __syncthreads();
    for (int i = tid; i < B_DIM; i += 256) {
        atomicAdd(&counts[albl[i]], 2);
        inA[albl[i]] = 1;
        atomicAdd(&counts[nlbl[i]], 1);
    }
    __syncthreads();
    float intra = 0.f;
    if (tid < NCLS) {
        int c = tid;
        float cnt = (float)counts[c];
        if (inA[c] && counts[c] > 1)
            intra = T[c * NCLS + c] / fmaxf(cnt * (cnt - 1.f), 1.f);
    }
    float inter = 0.f;
    for (int x = tid; x < NCLS * NCLS; x += 256) {
        int c1 = x >> 6, c2 = x & 63;
        if (c1 < c2 && inA[c1] && inA[c2]) {
            float pn = (float)counts[c1] * (float)counts[c2];
            if (pn > 0.f) inter += fmaxf(MARGIN_F - T[x] / fmaxf(pn, 1.f), 0.f);
        }
    }
    float intraAll = block_reduce_sum(intra, sred);
    float interAll = block_reduce_sum(inter, sred);
    if (tid == 0) {
        float trip = scal[0] / (float)B_DIM;
        float hard = (scal[2] > 0.f) ? scal[1] / fmaxf(scal[2], 1.f) : 0.f;
        float sh   = (scal[4] > 0.f) ? scal[3] / fmaxf(scal[4], 1.f) : 0.f;
        out[0] = trip + hard + sh + 0.1f * intraAll + 0.1f * interAll;
    }
}

// ---------------- launch ----------------
extern "C" void kernel_launch(void* const* d_in, const int* in_sizes, int n_in,
                              void* d_out, int out_size, void* d_ws, size_t ws_size,
                              hipStream_t stream) {
    const float* A  = (const float*)d_in[0];
    const float* P  = (const float*)d_in[1];
    const float* Ng = (const float*)d_in[2];
    const int* albl = (const int*)d_in[3];
    const int* nlbl = (const int*)d_in[4];
    char* ws = (char*)d_ws;
    // workspace layout (bytes)
    __bf16* Eb   = (__bf16*)(ws);                     // 3072*2048*2 = 12,582,912
    float* G     = (float*)(ws + 12582912);           // 3072*3072*4 = 37,748,736
    float* norms = (float*)(ws + 50331648);           // 3072*4
    float* T     = (float*)(ws + 50343936);           // 64*64*4
    float* scal  = (float*)(ws + 50360320);           // 8 floats (32 B)
    int*   lab   = (int*)(ws + 50360352);             // 3072*4 packed labels
    float* out   = (float*)d_out;

    hipLaunchKernelGGL(zero_kernel, dim3(16), dim3(256), 0, stream, T, scal, albl, nlbl, lab);
    hipLaunchKernelGGL(prep_kernel, dim3(B_DIM), dim3(256), 0, stream, A, P, Ng, Eb, norms, scal);
    hipLaunchKernelGGL(gram_gemm, dim3(NB128 * (NB128 + 1) / 2), dim3(256), 0, stream, Eb, G);
    hipLaunchKernelGGL(mirror_kernel, dim3((NB128 * (NB128 - 1) / 2) * 4), dim3(256), 0, stream, G);
    hipLaunchKernelGGL(tsumv_kernel, dim3((N_TOT - B_DIM) / 2), dim3(512), 0, stream, G, norms, lab, T);
    hipLaunchKernelGGL(minev_kernel, dim3(B_DIM), dim3(512), 0, stream, G, norms, lab, T, scal);
    hipLaunchKernelGGL(finalize_kernel, dim3(1), dim3(256), 0, stream, T, albl, nlbl, scal, out);
}

// Round 9
// 259.954 us; speedup vs baseline: 1.0250x; 1.0250x over previous
//
#include <hip/hip_runtime.h>
#include <hip/hip_bf16.h>
#include <stdint.h>

#define D_DIM 2048
#define B_DIM 1024
#define N_TOT 3072
#define NCLS 64
#define NB128 (N_TOT / 128)   // 24 tiles per side
#define MARGIN_F 0.8f
#define BIG_F 1e30f

typedef float f32x4 __attribute__((ext_vector_type(4)));
typedef int   i32x4 __attribute__((ext_vector_type(4)));
typedef __bf16 bf16x8 __attribute__((ext_vector_type(8)));

// async global->LDS, 16B per lane (m97 staging pattern).
__device__ __forceinline__ void gld_lds16(const __bf16* g, __bf16* l) {
    __builtin_amdgcn_global_load_lds(
        (const __attribute__((address_space(1))) void*)g,
        (__attribute__((address_space(3))) void*)l,
        16, 0, 0);
}

// ---------------- reduction helpers ----------------
__device__ inline float block_reduce_sum(float v, float* sred) {
    int tid = threadIdx.x;
    sred[tid] = v; __syncthreads();
    for (int s = 128; s > 0; s >>= 1) {
        if (tid < s) sred[tid] = sred[tid] + sred[tid + s];
        __syncthreads();
    }
    float r = sred[0]; __syncthreads();
    return r;
}
__device__ inline float block_sum4(float v, float* tmp4, int lane, int wave) {
    #pragma unroll
    for (int off = 32; off > 0; off >>= 1) v += __shfl_down(v, off);
    __syncthreads();
    if (lane == 0) tmp4[wave] = v;
    __syncthreads();
    return tmp4[0] + tmp4[1] + tmp4[2] + tmp4[3];
}
__device__ inline float wave_max(float v) {
    #pragma unroll
    for (int off = 32; off > 0; off >>= 1) v = fmaxf(v, __shfl_xor(v, off));
    return v;
}
__device__ inline float wave_min(float v) {
    #pragma unroll
    for (int off = 32; off > 0; off >>= 1) v = fminf(v, __shfl_xor(v, off));
    return v;
}

__device__ inline int label_of(int j, const int* __restrict__ albl, const int* __restrict__ nlbl) {
    return (j < 2 * B_DIM) ? albl[j & (B_DIM - 1)] : nlbl[j - 2 * B_DIM];
}

__device__ inline float sq8(f32x4 a, f32x4 b) {
    return a[0]*a[0] + a[1]*a[1] + a[2]*a[2] + a[3]*a[3]
         + b[0]*b[0] + b[1]*b[1] + b[2]*b[2] + b[3]*b[3];
}
__device__ inline void st_bf8(__bf16* dst, f32x4 v0, f32x4 v1) {
    bf16x8 o;
    o[0] = (__bf16)v0[0]; o[1] = (__bf16)v0[1]; o[2] = (__bf16)v0[2]; o[3] = (__bf16)v0[3];
    o[4] = (__bf16)v1[0]; o[5] = (__bf16)v1[1]; o[6] = (__bf16)v1[2]; o[7] = (__bf16)v1[3];
    *(bf16x8*)dst = o;
}

// ---------------- 0: zero accumulators + pack labels ----------------
__global__ __launch_bounds__(256) void zero_kernel(
        float* __restrict__ T, float* __restrict__ scal,
        const int* __restrict__ albl, const int* __restrict__ nlbl, int* __restrict__ lab) {
    int t = blockIdx.x * 256 + threadIdx.x;
    if (t < NCLS * NCLS) T[t] = 0.f;
    if (t < 8) scal[t] = 0.f;
    if (t < N_TOT) lab[t] = label_of(t, albl, nlbl);
}

// ---------------- 1: fused prep: bf16 convert + norms + exact triplet term ----------------
__global__ __launch_bounds__(256) void prep_kernel(
        const float* __restrict__ A, const float* __restrict__ P, const float* __restrict__ Ng,
        __bf16* __restrict__ Eb, float* __restrict__ norms, float* __restrict__ scal) {
    __shared__ float tmp4[4];
    int i = blockIdx.x, tid = threadIdx.x;
    int lane = tid & 63, wave = tid >> 6;
    const f32x4* a4 = (const f32x4*)(A + (size_t)i * D_DIM);
    const f32x4* p4 = (const f32x4*)(P + (size_t)i * D_DIM);
    const f32x4* n4 = (const f32x4*)(Ng + (size_t)i * D_DIM);
    f32x4 av0 = a4[tid * 2], av1 = a4[tid * 2 + 1];
    f32x4 pv0 = p4[tid * 2], pv1 = p4[tid * 2 + 1];
    f32x4 nv0 = n4[tid * 2], nv1 = n4[tid * 2 + 1];
    float sa = sq8(av0, av1), sp = sq8(pv0, pv1), sn = sq8(nv0, nv1);
    f32x4 dp0 = av0 - pv0, dp1 = av1 - pv1;
    f32x4 dn0 = av0 - nv0, dn1 = av1 - nv1;
    float pd = sq8(dp0, dp1), nd = sq8(dn0, dn1);
    st_bf8(Eb + (size_t)i * D_DIM + tid * 8, av0, av1);
    st_bf8(Eb + (size_t)(B_DIM + i) * D_DIM + tid * 8, pv0, pv1);
    st_bf8(Eb + (size_t)(2 * B_DIM + i) * D_DIM + tid * 8, nv0, nv1);
    float saT = block_sum4(sa, tmp4, lane, wave);
    float spT = block_sum4(sp, tmp4, lane, wave);
    float snT = block_sum4(sn, tmp4, lane, wave);
    float pdT = block_sum4(pd, tmp4, lane, wave);
    float ndT = block_sum4(nd, tmp4, lane, wave);
    if (tid == 0) {
        norms[i] = saT;
        norms[B_DIM + i] = spT;
        norms[2 * B_DIM + i] = snT;
        atomicAdd(&scal[0], fmaxf(pdT - ndT + MARGIN_F, 0.f));
    }
}

// ---------------- 2: bf16 MFMA Gram, upper triangle, global_load_lds staging (m97 structure) ----
__global__ __launch_bounds__(256) void gram_gemm(const __bf16* __restrict__ Eb, float* __restrict__ G) {
    __shared__ __bf16 As[128 * 32] __attribute__((aligned(16)));
    __shared__ __bf16 Bs[128 * 32] __attribute__((aligned(16)));
    int tid = threadIdx.x, lane = tid & 63, wave = tid >> 6;
    int by = 0, rem = blockIdx.x;
    while (rem >= NB128 - by) { rem -= (NB128 - by); ++by; }
    int bx = by + rem;
    size_t row0 = (size_t)by * 128, col0 = (size_t)bx * 128;
    int wr = wave >> 1, wc = wave & 1;
    f32x4 acc[4][4];
    #pragma unroll
    for (int m = 0; m < 4; ++m)
        #pragma unroll
        for (int n = 0; n < 4; ++n) acc[m][n] = (f32x4){0.f, 0.f, 0.f, 0.f};

    int rl = lane & 15;
    int kg = (lane >> 4) * 8;
    int srow = lane >> 2, scol = (lane & 3) * 8;
    const __bf16* gA0 = Eb + (row0 + wave * 32 + srow) * D_DIM + scol;
    const __bf16* gA1 = gA0 + 16 * D_DIM;
    const __bf16* gB0 = Eb + (col0 + wave * 32 + srow) * D_DIM + scol;
    const __bf16* gB1 = gB0 + 16 * D_DIM;
    __bf16* lA0 = &As[(wave * 32) * 32];
    __bf16* lA1 = &As[(wave * 32 + 16) * 32];
    __bf16* lB0 = &Bs[(wave * 32) * 32];
    __bf16* lB1 = &Bs[(wave * 32 + 16) * 32];

    for (int k0 = 0; k0 < D_DIM; k0 += 32) {
        __syncthreads();
        gld_lds16(gA0 + k0, lA0);
        gld_lds16(gA1 + k0, lA1);
        gld_lds16(gB0 + k0, lB0);
        gld_lds16(gB1 + k0, lB1);
        __syncthreads();
        bf16x8 af[4], bf[4];
        #pragma unroll
        for (int m = 0; m < 4; ++m)
            af[m] = *(const bf16x8*)&As[(wr * 64 + m * 16 + rl) * 32 + kg];
        #pragma unroll
        for (int n = 0; n < 4; ++n)
            bf[n] = *(const bf16x8*)&Bs[(wc * 64 + n * 16 + rl) * 32 + kg];
        #pragma unroll
        for (int m = 0; m < 4; ++m)
            #pragma unroll
            for (int n = 0; n < 4; ++n)
                acc[m][n] = __builtin_amdgcn_mfma_f32_16x16x32_bf16(af[m], bf[n], acc[m][n], 0, 0, 0);
    }
    int rg = (lane >> 4) * 4;
    #pragma unroll
    for (int m = 0; m < 4; ++m)
        #pragma unroll
        for (int n = 0; n < 4; ++n)
            #pragma unroll
            for (int r = 0; r < 4; ++r) {
                size_t row = row0 + wr * 64 + m * 16 + rg + r;
                size_t col = col0 + wc * 64 + n * 16 + rl;
                G[row * N_TOT + col] = acc[m][n][r];
            }
}

// ---------------- 3: mirror upper triangle into lower (64x64 LDS transpose tiles) ----------------
__global__ __launch_bounds__(256) void mirror_kernel(float* __restrict__ G) {
    __shared__ float s[64 * 65];
    int b = blockIdx.x;
    int p = b >> 2, q = b & 3;
    int bj = 0, rem = p;
    while (rem >= NB128 - 1 - bj) { rem -= (NB128 - 1 - bj); ++bj; }
    int bi = bj + 1 + rem;
    int ti = bi * 2 + (q >> 1), tj = bj * 2 + (q & 1);
    int tid = threadIdx.x;
    int c = tid & 63, r4 = tid >> 6;
    const float* src = G + ((size_t)tj * 64) * N_TOT + (size_t)ti * 64;
    float* dst = G + ((size_t)ti * 64) * N_TOT + (size_t)tj * 64;
    #pragma unroll
    for (int rr = 0; rr < 16; ++rr) {
        int row = rr * 4 + r4;
        s[row * 65 + c] = src[(size_t)row * N_TOT + c];
    }
    __syncthreads();
    #pragma unroll
    for (int rr = 0; rr < 16; ++rr) {
        int row = rr * 4 + r4;
        dst[(size_t)row * N_TOT + c] = s[c * 65 + row];
    }
}

// ---------------- 4: vectorized T-binning, rows B..N, per-wave bins ----------
__global__ __launch_bounds__(512) void tsumv_kernel(
        const float* __restrict__ G, const float* __restrict__ norms,
        const int* __restrict__ lab, float* __restrict__ T) {
    __shared__ float tlw[8 * 2 * NCLS];   // [wave][row][cls]
    int tid = threadIdx.x, wave = tid >> 6;
    int r0 = B_DIM + blockIdx.x * 2;
    tlw[tid] = 0.f;
    tlw[512 + tid] = 0.f;
    __syncthreads();
    // register-cache labels+norms of this thread's column groups across both rows
    int jA = tid * 4;
    f32x4 njA = *(const f32x4*)&norms[jA];
    i32x4 ljA = *(const i32x4*)&lab[jA];
    int jB = 2048 + tid * 4;
    f32x4 njB; i32x4 ljB;
    bool hasB = (tid < 256);
    if (hasB) {
        njB = *(const f32x4*)&norms[jB];
        ljB = *(const i32x4*)&lab[jB];
    }
    #pragma unroll
    for (int rr = 0; rr < 2; ++rr) {
        int r = r0 + rr;
        float nr = norms[r];
        const float* Grow = G + (size_t)r * N_TOT;
        float* bins = &tlw[(wave * 2 + rr) * NCLS];
        {
            f32x4 g = *(const f32x4*)&Grow[jA];
            f32x4 d2 = nr + njA - 2.f * g;
            atomicAdd(&bins[ljA[0]], sqrtf(fmaxf(d2[0], 1e-8f)));
            atomicAdd(&bins[ljA[1]], sqrtf(fmaxf(d2[1], 1e-8f)));
            atomicAdd(&bins[ljA[2]], sqrtf(fmaxf(d2[2], 1e-8f)));
            atomicAdd(&bins[ljA[3]], sqrtf(fmaxf(d2[3], 1e-8f)));
        }
        if (hasB) {
            f32x4 g = *(const f32x4*)&Grow[jB];
            f32x4 d2 = nr + njB - 2.f * g;
            atomicAdd(&bins[ljB[0]], sqrtf(fmaxf(d2[0], 1e-8f)));
            atomicAdd(&bins[ljB[1]], sqrtf(fmaxf(d2[1], 1e-8f)));
            atomicAdd(&bins[ljB[2]], sqrtf(fmaxf(d2[2], 1e-8f)));
            atomicAdd(&bins[ljB[3]], sqrtf(fmaxf(d2[3], 1e-8f)));
        }
    }
    __syncthreads();
    if (tid < 2 * NCLS) {
        int rr = tid >> 6, c = tid & 63;
        float s = 0.f;
        #pragma unroll
        for (int w = 0; w < 8; ++w) s += tlw[(w * 2 + rr) * NCLS + c];
        if (s != 0.f) atomicAdd(&T[lab[r0 + rr] * NCLS + c], s);
    }
}

// ---------------- 5: mining + successor via count-bucket order statistics ----------
// Identity: cand(q) = min{v : v > q} = min over bins j >= m(q), where cnt(v) = #{queries < v},
// bin j = {v : cnt(v) = j}, m(q) = #{queries <= q}. Phase 2 is now O(N*~P/64 VALU) lane-parallel
// over ELEMENTS (R8's readlane scan was lane-parallel over queries: 4096 issue-cyc/wave; this
// is ~1000) + 8 atomicMin/thread + O(P^2) wave-0 epilogue.
__global__ __launch_bounds__(512) void minev_kernel(
        const float* __restrict__ G, const float* __restrict__ norms,
        const int* __restrict__ lab, float* __restrict__ T, float* __restrict__ scal) {
    __shared__ float tlw[8 * NCLS];        // per-wave T bins
    __shared__ float qlist[128];
    __shared__ unsigned binmin[130];       // binmin[cnt] as ordered uint (floats >= 0)
    __shared__ float sufmin[130];
    __shared__ float hpw[8], hnw[8];
    __shared__ int pcount;
    int i = blockIdx.x, tid = threadIdx.x;
    int lane = tid & 63, wave = tid >> 6;
    if (tid == 0) pcount = 0;
    tlw[tid] = 0.f;                        // 512 threads cover 8*64 exactly
    if (tid < 130) binmin[tid] = 0x7F800000u;   // +inf
    __syncthreads();
    int la = lab[i];
    float ni = norms[i];
    const float* Grow = G + (size_t)i * N_TOT;
    float hp = -BIG_F, hn = BIG_F;
    float* bins = &tlw[wave * NCLS];

    // ---- phase 1: distances, T-bins, qlist; dn values stay in registers ----
    f32x4 dnA, dnB;
    {   // group A: j = tid*4 (covers 0..2047)
        int j = tid * 4;
        f32x4 g = *(const f32x4*)&Grow[j];
        f32x4 nj = *(const f32x4*)&norms[j];
        i32x4 lj = *(const i32x4*)&lab[j];
        f32x4 d2 = ni + nj - 2.f * g;
        float d0 = sqrtf(fmaxf(d2[0], 1e-8f));
        float d1 = sqrtf(fmaxf(d2[1], 1e-8f));
        float dd2 = sqrtf(fmaxf(d2[2], 1e-8f));
        float d3 = sqrtf(fmaxf(d2[3], 1e-8f));
        atomicAdd(&bins[lj[0]], d0);
        atomicAdd(&bins[lj[1]], d1);
        atomicAdd(&bins[lj[2]], dd2);
        atomicAdd(&bins[lj[3]], d3);
        bool n0 = lj[0] != la, n1 = lj[1] != la, n2 = lj[2] != la, n3 = lj[3] != la;
        dnA = (f32x4){ n0 ? d0 : BIG_F, n1 ? d1 : BIG_F, n2 ? dd2 : BIG_F, n3 ? d3 : BIG_F };
        hn = fminf(hn, fminf(fminf(dnA[0], dnA[1]), fminf(dnA[2], dnA[3])));
        if (!n0 && j + 0 != i) { hp = fmaxf(hp, d0); int p = atomicAdd(&pcount, 1); if (p < 128) qlist[p] = d0; }
        if (!n1 && j + 1 != i) { hp = fmaxf(hp, d1); int p = atomicAdd(&pcount, 1); if (p < 128) qlist[p] = d1; }
        if (!n2 && j + 2 != i) { hp = fmaxf(hp, dd2); int p = atomicAdd(&pcount, 1); if (p < 128) qlist[p] = dd2; }
        if (!n3 && j + 3 != i) { hp = fmaxf(hp, d3); int p = atomicAdd(&pcount, 1); if (p < 128) qlist[p] = d3; }
    }
    if (tid < 256) {   // group B: j = 2048 + tid*4 (covers 2048..3071)
        int j = 2048 + tid * 4;
        f32x4 g = *(const f32x4*)&Grow[j];
        f32x4 nj = *(const f32x4*)&norms[j];
        i32x4 lj = *(const i32x4*)&lab[j];
        f32x4 d2 = ni + nj - 2.f * g;
        float d0 = sqrtf(fmaxf(d2[0], 1e-8f));
        float d1 = sqrtf(fmaxf(d2[1], 1e-8f));
        float dd2 = sqrtf(fmaxf(d2[2], 1e-8f));
        float d3 = sqrtf(fmaxf(d2[3], 1e-8f));
        atomicAdd(&bins[lj[0]], d0);
        atomicAdd(&bins[lj[1]], d1);
        atomicAdd(&bins[lj[2]], dd2);
        atomicAdd(&bins[lj[3]], d3);
        bool n0 = lj[0] != la, n1 = lj[1] != la, n2 = lj[2] != la, n3 = lj[3] != la;
        dnB = (f32x4){ n0 ? d0 : BIG_F, n1 ? d1 : BIG_F, n2 ? dd2 : BIG_F, n3 ? d3 : BIG_F };
        hn = fminf(hn, fminf(fminf(dnB[0], dnB[1]), fminf(dnB[2], dnB[3])));
        if (!n0 && j + 0 != i) { hp = fmaxf(hp, d0); int p = atomicAdd(&pcount, 1); if (p < 128) qlist[p] = d0; }
        if (!n1 && j + 1 != i) { hp = fmaxf(hp, d1); int p = atomicAdd(&pcount, 1); if (p < 128) qlist[p] = d1; }
        if (!n2 && j + 2 != i) { hp = fmaxf(hp, dd2); int p = atomicAdd(&pcount, 1); if (p < 128) qlist[p] = dd2; }
        if (!n3 && j + 3 != i) { hp = fmaxf(hp, d3); int p = atomicAdd(&pcount, 1); if (p < 128) qlist[p] = d3; }
    } else {
        dnB = (f32x4){BIG_F, BIG_F, BIG_F, BIG_F};
    }
    float hpw_ = wave_max(hp), hnw_ = wave_min(hn);
    if (lane == 0) { hpw[wave] = hpw_; hnw[wave] = hnw_; }
    __syncthreads();                     // publish bins, qlist, pcount, hpw/hnw

    // T-bin flush (row label fixed)
    if (tid < NCLS) {
        float s = 0.f;
        #pragma unroll
        for (int w = 0; w < 8; ++w) s += tlw[w * NCLS + tid];
        if (s != 0.f) atomicAdd(&T[la * NCLS + tid], s);
    }

    int P = min(pcount, 128);
    if (P > 0) {
        // ---- count phase: per element, cnt = #{queries < v} (strict); atomicMin into bin ----
        int cA0 = 0, cA1 = 0, cA2 = 0, cA3 = 0, cB0 = 0, cB1 = 0, cB2 = 0, cB3 = 0;
        for (int k = 0; k < P; ++k) {
            float qk = qlist[k];         // broadcast read
            cA0 += (qk < dnA[0]); cA1 += (qk < dnA[1]);
            cA2 += (qk < dnA[2]); cA3 += (qk < dnA[3]);
            cB0 += (qk < dnB[0]); cB1 += (qk < dnB[1]);
            cB2 += (qk < dnB[2]); cB3 += (qk < dnB[3]);
        }
        atomicMin(&binmin[cA0], __float_as_uint(dnA[0]));
        atomicMin(&binmin[cA1], __float_as_uint(dnA[1]));
        atomicMin(&binmin[cA2], __float_as_uint(dnA[2]));
        atomicMin(&binmin[cA3], __float_as_uint(dnA[3]));
        atomicMin(&binmin[cB0], __float_as_uint(dnB[0]));
        atomicMin(&binmin[cB1], __float_as_uint(dnB[1]));
        atomicMin(&binmin[cB2], __float_as_uint(dnB[2]));
        atomicMin(&binmin[cB3], __float_as_uint(dnB[3]));
        __syncthreads();

        // ---- suffix-min over bins 0..P (wave 0; chunked shfl scan, high chunk first) ----
        if (wave == 0) {
            int nb = P + 1;
            int nch = (nb + 63) >> 6;
            float carry = BIG_F;
            for (int ch = nch - 1; ch >= 0; --ch) {
                int idx = ch * 64 + lane;
                float v = (idx < nb) ? __uint_as_float(binmin[idx]) : BIG_F;
                #pragma unroll
                for (int off = 1; off < 64; off <<= 1)
                    v = fminf(v, __shfl_down(v, off));   // out-of-range shfl returns own value
                v = fminf(v, carry);
                if (idx < nb) sufmin[idx] = v;
                carry = __shfl(v, 0);
            }
            // ---- query eval: lane k handles query k; m(q) = #{q' <= q}; cand = sufmin[m] ----
            float s = 0.f, n = 0.f;
            for (int base = 0; base < P; base += 64) {
                int k = base + lane;
                if (k < P) {
                    float q = qlist[k];
                    int m = 0;
                    for (int j = 0; j < P; ++j) m += (qlist[j] <= q);
                    float cand = sufmin[m];              // m in [1, P]
                    if (cand < 1e29f && cand < q + MARGIN_F) { s += q - cand + MARGIN_F; n += 1.f; }
                }
            }
            #pragma unroll
            for (int off = 32; off > 0; off >>= 1) {
                s += __shfl_down(s, off);
                n += __shfl_down(n, off);
            }
            if (lane == 0) {
                float hpAll = hpw[0], hnAll = hnw[0];
                #pragma unroll
                for (int w = 1; w < 8; ++w) { hpAll = fmaxf(hpAll, hpw[w]); hnAll = fminf(hnAll, hnw[w]); }
                if (hnAll < 1e29f) {
                    atomicAdd(&scal[1], fmaxf(hpAll - hnAll + MARGIN_F, 0.f));
                    atomicAdd(&scal[2], 1.f);
                }
                if (s != 0.f || n != 0.f) {
                    atomicAdd(&scal[3], s);
                    atomicAdd(&scal[4], n);
                }
            }
        }
    }
}

// ---------------- 6: finalize: counts, intra/inter, combine ----------------
__global__ __launch_bounds__(256) void finalize_kernel(
        const float* __restrict__ T, const int* __restrict__ albl, const int* __restrict__ nlbl,
        const float* __restrict__ scal, float* __restrict__ out) {
    __shared__ int counts[NCLS];
    __shared__ int inA[NCLS];
    __shared__ float sred[256];
    int tid = threadIdx.x;
    if (tid < NCLS) { counts[tid] = 0; inA[tid] = 0; }
    __syncthreads();
    for (int i = tid; i < B_DIM; i += 256) {
        atomicAdd(&counts[albl[i]], 2);
        inA[albl[i]] = 1;
        atomicAdd(&counts[nlbl[i]], 1);
    }
    __syncthreads();
    float intra = 0.f;
    if (tid < NCLS) {
        int c = tid;
        float cnt = (float)counts[c];
        if (inA[c] && counts[c] > 1)
            intra = T[c * NCLS + c] / fmaxf(cnt * (cnt - 1.f), 1.f);
    }
    float inter = 0.f;
    for (int x = tid; x < NCLS * NCLS; x += 256) {
        int c1 = x >> 6, c2 = x & 63;
        if (c1 < c2 && inA[c1] && inA[c2]) {
            float pn = (float)counts[c1] * (float)counts[c2];
            if (pn > 0.f) inter += fmaxf(MARGIN_F - T[x] / fmaxf(pn, 1.f), 0.f);
        }
    }
    float intraAll = block_reduce_sum(intra, sred);
    float interAll = block_reduce_sum(inter, sred);
    if (tid == 0) {
        float trip = scal[0] / (float)B_DIM;
        float hard = (scal[2] > 0.f) ? scal[1] / fmaxf(scal[2], 1.f) : 0.f;
        float sh   = (scal[4] > 0.f) ? scal[3] / fmaxf(scal[4], 1.f) : 0.f;
        out[0] = trip + hard + sh + 0.1f * intraAll + 0.1f * interAll;
    }
}

// ---------------- launch ----------------
extern "C" void kernel_launch(void* const* d_in, const int* in_sizes, int n_in,
                              void* d_out, int out_size, void* d_ws, size_t ws_size,
                              hipStream_t stream) {
    const float* A  = (const float*)d_in[0];
    const float* P  = (const float*)d_in[1];
    const float* Ng = (const float*)d_in[2];
    const int* albl = (const int*)d_in[3];
    const int* nlbl = (const int*)d_in[4];
    char* ws = (char*)d_ws;
    // workspace layout (bytes)
    __bf16* Eb   = (__bf16*)(ws);                     // 3072*2048*2 = 12,582,912
    float* G     = (float*)(ws + 12582912);           // 3072*3072*4 = 37,748,736
    float* norms = (float*)(ws + 50331648);           // 3072*4
    float* T     = (float*)(ws + 50343936);           // 64*64*4
    float* scal  = (float*)(ws + 50360320);           // 8 floats (32 B)
    int*   lab   = (int*)(ws + 50360352);             // 3072*4 packed labels
    float* out   = (float*)d_out;

    hipLaunchKernelGGL(zero_kernel, dim3(16), dim3(256), 0, stream, T, scal, albl, nlbl, lab);
    hipLaunchKernelGGL(prep_kernel, dim3(B_DIM), dim3(256), 0, stream, A, P, Ng, Eb, norms, scal);
    hipLaunchKernelGGL(gram_gemm, dim3(NB128 * (NB128 + 1) / 2), dim3(256), 0, stream, Eb, G);
    hipLaunchKernelGGL(mirror_kernel, dim3((NB128 * (NB128 - 1) / 2) * 4), dim3(256), 0, stream, G);
    hipLaunchKernelGGL(tsumv_kernel, dim3((N_TOT - B_DIM) / 2), dim3(512), 0, stream, G, norms, lab, T);
    hipLaunchKernelGGL(minev_kernel, dim3(B_DIM), dim3(512), 0, stream, G, norms, lab, T, scal);
    hipLaunchKernelGGL(finalize_kernel, dim3(1), dim3(256), 0, stream, T, albl, nlbl, scal, out);
}

// Round 10
// 248.595 us; speedup vs baseline: 1.0718x; 1.0457x over previous
//
#include <hip/hip_runtime.h>
#include <hip/hip_bf16.h>
#include <stdint.h>

#define D_DIM 2048
#define B_DIM 1024
#define N_TOT 3072
#define NCLS 64
#define NB128 (N_TOT / 128)   // 24 tiles per side
#define MARGIN_F 0.8f
#define BIG_F 1e30f

typedef float f32x4 __attribute__((ext_vector_type(4)));
typedef int   i32x4 __attribute__((ext_vector_type(4)));
typedef __bf16 bf16x8 __attribute__((ext_vector_type(8)));

// async global->LDS, 16B per lane (m97 staging pattern).
__device__ __forceinline__ void gld_lds16(const __bf16* g, __bf16* l) {
    __builtin_amdgcn_global_load_lds(
        (const __attribute__((address_space(1))) void*)g,
        (__attribute__((address_space(3))) void*)l,
        16, 0, 0);
}

// ---------------- reduction helpers ----------------
__device__ inline float block_reduce_sum(float v, float* sred) {
    int tid = threadIdx.x;
    sred[tid] = v; __syncthreads();
    for (int s = 128; s > 0; s >>= 1) {
        if (tid < s) sred[tid] = sred[tid] + sred[tid + s];
        __syncthreads();
    }
    float r = sred[0]; __syncthreads();
    return r;
}
__device__ inline float block_sum4(float v, float* tmp4, int lane, int wave) {
    #pragma unroll
    for (int off = 32; off > 0; off >>= 1) v += __shfl_down(v, off);
    __syncthreads();
    if (lane == 0) tmp4[wave] = v;
    __syncthreads();
    return tmp4[0] + tmp4[1] + tmp4[2] + tmp4[3];
}
__device__ inline float wave_max(float v) {
    #pragma unroll
    for (int off = 32; off > 0; off >>= 1) v = fmaxf(v, __shfl_xor(v, off));
    return v;
}
__device__ inline float wave_min(float v) {
    #pragma unroll
    for (int off = 32; off > 0; off >>= 1) v = fminf(v, __shfl_xor(v, off));
    return v;
}

__device__ inline int label_of(int j, const int* __restrict__ albl, const int* __restrict__ nlbl) {
    return (j < 2 * B_DIM) ? albl[j & (B_DIM - 1)] : nlbl[j - 2 * B_DIM];
}

__device__ inline float sq8(f32x4 a, f32x4 b) {
    return a[0]*a[0] + a[1]*a[1] + a[2]*a[2] + a[3]*a[3]
         + b[0]*b[0] + b[1]*b[1] + b[2]*b[2] + b[3]*b[3];
}
__device__ inline void st_bf8(__bf16* dst, f32x4 v0, f32x4 v1) {
    bf16x8 o;
    o[0] = (__bf16)v0[0]; o[1] = (__bf16)v0[1]; o[2] = (__bf16)v0[2]; o[3] = (__bf16)v0[3];
    o[4] = (__bf16)v1[0]; o[5] = (__bf16)v1[1]; o[6] = (__bf16)v1[2]; o[7] = (__bf16)v1[3];
    *(bf16x8*)dst = o;
}

// ---------------- 0: zero T + pack labels ----------------
__global__ __launch_bounds__(256) void zero_kernel(
        float* __restrict__ T,
        const int* __restrict__ albl, const int* __restrict__ nlbl, int* __restrict__ lab) {
    int t = blockIdx.x * 256 + threadIdx.x;
    if (t < NCLS * NCLS) T[t] = 0.f;
    if (t < N_TOT) lab[t] = label_of(t, albl, nlbl);
}

// ---------------- 1: fused prep: bf16 convert + norms + triplet partial (no atomics) -----------
__global__ __launch_bounds__(256) void prep_kernel(
        const float* __restrict__ A, const float* __restrict__ P, const float* __restrict__ Ng,
        __bf16* __restrict__ Eb, float* __restrict__ norms, float* __restrict__ pbT) {
    __shared__ float tmp4[4];
    int i = blockIdx.x, tid = threadIdx.x;
    int lane = tid & 63, wave = tid >> 6;
    const f32x4* a4 = (const f32x4*)(A + (size_t)i * D_DIM);
    const f32x4* p4 = (const f32x4*)(P + (size_t)i * D_DIM);
    const f32x4* n4 = (const f32x4*)(Ng + (size_t)i * D_DIM);
    f32x4 av0 = a4[tid * 2], av1 = a4[tid * 2 + 1];
    f32x4 pv0 = p4[tid * 2], pv1 = p4[tid * 2 + 1];
    f32x4 nv0 = n4[tid * 2], nv1 = n4[tid * 2 + 1];
    float sa = sq8(av0, av1), sp = sq8(pv0, pv1), sn = sq8(nv0, nv1);
    f32x4 dp0 = av0 - pv0, dp1 = av1 - pv1;
    f32x4 dn0 = av0 - nv0, dn1 = av1 - nv1;
    float pd = sq8(dp0, dp1), nd = sq8(dn0, dn1);
    st_bf8(Eb + (size_t)i * D_DIM + tid * 8, av0, av1);
    st_bf8(Eb + (size_t)(B_DIM + i) * D_DIM + tid * 8, pv0, pv1);
    st_bf8(Eb + (size_t)(2 * B_DIM + i) * D_DIM + tid * 8, nv0, nv1);
    float saT = block_sum4(sa, tmp4, lane, wave);
    float spT = block_sum4(sp, tmp4, lane, wave);
    float snT = block_sum4(sn, tmp4, lane, wave);
    float pdT = block_sum4(pd, tmp4, lane, wave);
    float ndT = block_sum4(nd, tmp4, lane, wave);
    if (tid == 0) {
        norms[i] = saT;
        norms[B_DIM + i] = spT;
        norms[2 * B_DIM + i] = snT;
        pbT[i] = fmaxf(pdT - ndT + MARGIN_F, 0.f);
    }
}

// ---------------- 2: Gram (upper triangle) + fused T-binning epilogue -----------
// Each block holds its 128x128 G-tile in acc registers; epilogue bins d=sqrt(nr+nc-2G)
// into LDS [64][64] class-pair sums (both orientations for off-diag: T is symmetric),
// then ~4096 distributed global atomics. G is written ONLY for by<8 (rows < 1024 —
// the only rows minev reads); G buffer is [1024][3072].
__global__ __launch_bounds__(256) void gram_gemm(
        const __bf16* __restrict__ Eb, float* __restrict__ G,
        const float* __restrict__ norms, const int* __restrict__ lab, float* __restrict__ T) {
    __shared__ __bf16 As[128 * 32] __attribute__((aligned(16)));
    __shared__ __bf16 Bs[128 * 32] __attribute__((aligned(16)));
    __shared__ float tb[NCLS * NCLS];
    __shared__ float rnorm[128], cnorm[128];
    __shared__ int rlabs[128], clabs[128];
    int tid = threadIdx.x, lane = tid & 63, wave = tid >> 6;
    int by = 0, rem = blockIdx.x;
    while (rem >= NB128 - by) { rem -= (NB128 - by); ++by; }
    int bx = by + rem;
    size_t row0 = (size_t)by * 128, col0 = (size_t)bx * 128;
    int wr = wave >> 1, wc = wave & 1;
    f32x4 acc[4][4];
    #pragma unroll
    for (int m = 0; m < 4; ++m)
        #pragma unroll
        for (int n = 0; n < 4; ++n) acc[m][n] = (f32x4){0.f, 0.f, 0.f, 0.f};

    // stage norms/labels for tile rows/cols + zero T bins
    if (tid < 128) { rnorm[tid] = norms[row0 + tid]; rlabs[tid] = lab[row0 + tid]; }
    else { int t = tid - 128; cnorm[t] = norms[col0 + t]; clabs[t] = lab[col0 + t]; }
    for (int x = tid; x < NCLS * NCLS; x += 256) tb[x] = 0.f;

    int rl = lane & 15;
    int kg = (lane >> 4) * 8;
    int srow = lane >> 2, scol = (lane & 3) * 8;
    const __bf16* gA0 = Eb + (row0 + wave * 32 + srow) * D_DIM + scol;
    const __bf16* gA1 = gA0 + 16 * D_DIM;
    const __bf16* gB0 = Eb + (col0 + wave * 32 + srow) * D_DIM + scol;
    const __bf16* gB1 = gB0 + 16 * D_DIM;
    __bf16* lA0 = &As[(wave * 32) * 32];
    __bf16* lA1 = &As[(wave * 32 + 16) * 32];
    __bf16* lB0 = &Bs[(wave * 32) * 32];
    __bf16* lB1 = &Bs[(wave * 32 + 16) * 32];

    for (int k0 = 0; k0 < D_DIM; k0 += 32) {
        __syncthreads();          // iter0: publishes staging/tb-init; later: prev ds_reads done
        gld_lds16(gA0 + k0, lA0);
        gld_lds16(gA1 + k0, lA1);
        gld_lds16(gB0 + k0, lB0);
        gld_lds16(gB1 + k0, lB1);
        __syncthreads();
        bf16x8 af[4], bf[4];
        #pragma unroll
        for (int m = 0; m < 4; ++m)
            af[m] = *(const bf16x8*)&As[(wr * 64 + m * 16 + rl) * 32 + kg];
        #pragma unroll
        for (int n = 0; n < 4; ++n)
            bf[n] = *(const bf16x8*)&Bs[(wc * 64 + n * 16 + rl) * 32 + kg];
        #pragma unroll
        for (int m = 0; m < 4; ++m)
            #pragma unroll
            for (int n = 0; n < 4; ++n)
                acc[m][n] = __builtin_amdgcn_mfma_f32_16x16x32_bf16(af[m], bf[n], acc[m][n], 0, 0, 0);
    }
    // C/D layout (HW-verified): col = lane&15, row = (lane>>4)*4 + reg
    int rg = (lane >> 4) * 4;
    bool offdiag = (by != bx);
    bool writeG = (by < 8);
    #pragma unroll
    for (int m = 0; m < 4; ++m)
        #pragma unroll
        for (int n = 0; n < 4; ++n) {
            int lcol = wc * 64 + n * 16 + rl;
            float cn = cnorm[lcol];
            int cl = clabs[lcol];
            #pragma unroll
            for (int r = 0; r < 4; ++r) {
                int lrow = wr * 64 + m * 16 + rg + r;
                float g = acc[m][n][r];
                float d = sqrtf(fmaxf(rnorm[lrow] + cn - 2.f * g, 1e-8f));
                int rlb = rlabs[lrow];
                atomicAdd(&tb[rlb * NCLS + cl], d);
                if (offdiag) atomicAdd(&tb[cl * NCLS + rlb], d);
                if (writeG) G[(row0 + lrow) * N_TOT + col0 + lcol] = g;
            }
        }
    __syncthreads();
    for (int x = tid; x < NCLS * NCLS; x += 256) {
        float v = tb[x];
        if (v != 0.f) atomicAdd(&T[x], v);
    }
}

// ---------------- 3: mirror (only tiles feeding minev rows < 1024) ----------------
// dst 64-tiles (ti,tj), ti>tj, ti<=15  <=>  128-pairs bi>bj, bi<=7: 28 pairs x 4 = 112 blocks.
__global__ __launch_bounds__(256) void mirror_kernel(float* __restrict__ G) {
    __shared__ float s[64 * 65];
    int b = blockIdx.x;
    int p = b >> 2, q = b & 3;
    int bj = 0, rem = p;
    while (rem >= 7 - bj) { rem -= (7 - bj); ++bj; }
    int bi = bj + 1 + rem;
    int ti = bi * 2 + (q >> 1), tj = bj * 2 + (q & 1);
    int tid = threadIdx.x;
    int c = tid & 63, r4 = tid >> 6;
    const float* src = G + ((size_t)tj * 64) * N_TOT + (size_t)ti * 64;  // upper tile (tj,ti)
    float* dst = G + ((size_t)ti * 64) * N_TOT + (size_t)tj * 64;        // lower tile (ti,tj)
    #pragma unroll
    for (int rr = 0; rr < 16; ++rr) {
        int row = rr * 4 + r4;
        s[row * 65 + c] = src[(size_t)row * N_TOT + c];
    }
    __syncthreads();
    #pragma unroll
    for (int rr = 0; rr < 16; ++rr) {
        int row = rr * 4 + r4;
        dst[(size_t)row * N_TOT + c] = s[c * 65 + row];
    }
}

// ---------------- 4: mining + successor (count-bucket); per-block partial outputs ----------
__global__ __launch_bounds__(512) void minev_kernel(
        const float* __restrict__ G, const float* __restrict__ norms,
        const int* __restrict__ lab, float* __restrict__ pb4) {
    __shared__ float qlist[128];
    __shared__ unsigned binmin[130];
    __shared__ float sufmin[130];
    __shared__ float hpw[8], hnw[8];
    __shared__ int pcount;
    int i = blockIdx.x, tid = threadIdx.x;
    int lane = tid & 63, wave = tid >> 6;
    if (tid == 0) pcount = 0;
    if (tid < 130) binmin[tid] = 0x7F800000u;   // +inf
    __syncthreads();
    int la = lab[i];
    float ni = norms[i];
    const float* Grow = G + (size_t)i * N_TOT;
    float hp = -BIG_F, hn = BIG_F;

    f32x4 dnA, dnB;
    {   // group A: j = tid*4 (0..2047)
        int j = tid * 4;
        f32x4 g = *(const f32x4*)&Grow[j];
        f32x4 nj = *(const f32x4*)&norms[j];
        i32x4 lj = *(const i32x4*)&lab[j];
        f32x4 d2 = ni + nj - 2.f * g;
        float d0 = sqrtf(fmaxf(d2[0], 1e-8f));
        float d1 = sqrtf(fmaxf(d2[1], 1e-8f));
        float dd2 = sqrtf(fmaxf(d2[2], 1e-8f));
        float d3 = sqrtf(fmaxf(d2[3], 1e-8f));
        bool n0 = lj[0] != la, n1 = lj[1] != la, n2 = lj[2] != la, n3 = lj[3] != la;
        dnA = (f32x4){ n0 ? d0 : BIG_F, n1 ? d1 : BIG_F, n2 ? dd2 : BIG_F, n3 ? d3 : BIG_F };
        hn = fminf(hn, fminf(fminf(dnA[0], dnA[1]), fminf(dnA[2], dnA[3])));
        if (!n0 && j + 0 != i) { hp = fmaxf(hp, d0); int p = atomicAdd(&pcount, 1); if (p < 128) qlist[p] = d0; }
        if (!n1 && j + 1 != i) { hp = fmaxf(hp, d1); int p = atomicAdd(&pcount, 1); if (p < 128) qlist[p] = d1; }
        if (!n2 && j + 2 != i) { hp = fmaxf(hp, dd2); int p = atomicAdd(&pcount, 1); if (p < 128) qlist[p] = dd2; }
        if (!n3 && j + 3 != i) { hp = fmaxf(hp, d3); int p = atomicAdd(&pcount, 1); if (p < 128) qlist[p] = d3; }
    }
    if (tid < 256) {   // group B: j = 2048 + tid*4 (2048..3071)
        int j = 2048 + tid * 4;
        f32x4 g = *(const f32x4*)&Grow[j];
        f32x4 nj = *(const f32x4*)&norms[j];
        i32x4 lj = *(const i32x4*)&lab[j];
        f32x4 d2 = ni + nj - 2.f * g;
        float d0 = sqrtf(fmaxf(d2[0], 1e-8f));
        float d1 = sqrtf(fmaxf(d2[1], 1e-8f));
        float dd2 = sqrtf(fmaxf(d2[2], 1e-8f));
        float d3 = sqrtf(fmaxf(d2[3], 1e-8f));
        bool n0 = lj[0] != la, n1 = lj[1] != la, n2 = lj[2] != la, n3 = lj[3] != la;
        dnB = (f32x4){ n0 ? d0 : BIG_F, n1 ? d1 : BIG_F, n2 ? dd2 : BIG_F, n3 ? d3 : BIG_F };
        hn = fminf(hn, fminf(fminf(dnB[0], dnB[1]), fminf(dnB[2], dnB[3])));
        if (!n0 && j + 0 != i) { hp = fmaxf(hp, d0); int p = atomicAdd(&pcount, 1); if (p < 128) qlist[p] = d0; }
        if (!n1 && j + 1 != i) { hp = fmaxf(hp, d1); int p = atomicAdd(&pcount, 1); if (p < 128) qlist[p] = d1; }
        if (!n2 && j + 2 != i) { hp = fmaxf(hp, dd2); int p = atomicAdd(&pcount, 1); if (p < 128) qlist[p] = dd2; }
        if (!n3 && j + 3 != i) { hp = fmaxf(hp, d3); int p = atomicAdd(&pcount, 1); if (p < 128) qlist[p] = d3; }
    } else {
        dnB = (f32x4){BIG_F, BIG_F, BIG_F, BIG_F};
    }
    float hpw_ = wave_max(hp), hnw_ = wave_min(hn);
    if (lane == 0) { hpw[wave] = hpw_; hnw[wave] = hnw_; }
    __syncthreads();                     // publish qlist, pcount, hpw/hnw

    int P = min(pcount, 128);
    if (P > 0) {
        // count phase: cnt = #{queries < v} strict; atomicMin only for REAL values
        // (unguarded BIG values funneled 1000+ atomics onto binmin[P] in R9: 1.4M conflicts)
        int cA0 = 0, cA1 = 0, cA2 = 0, cA3 = 0, cB0 = 0, cB1 = 0, cB2 = 0, cB3 = 0;
        for (int k = 0; k < P; ++k) {
            float qk = qlist[k];         // broadcast read
            cA0 += (qk < dnA[0]); cA1 += (qk < dnA[1]);
            cA2 += (qk < dnA[2]); cA3 += (qk < dnA[3]);
            cB0 += (qk < dnB[0]); cB1 += (qk < dnB[1]);
            cB2 += (qk < dnB[2]); cB3 += (qk < dnB[3]);
        }
        if (dnA[0] < 1e29f) atomicMin(&binmin[cA0], __float_as_uint(dnA[0]));
        if (dnA[1] < 1e29f) atomicMin(&binmin[cA1], __float_as_uint(dnA[1]));
        if (dnA[2] < 1e29f) atomicMin(&binmin[cA2], __float_as_uint(dnA[2]));
        if (dnA[3] < 1e29f) atomicMin(&binmin[cA3], __float_as_uint(dnA[3]));
        if (dnB[0] < 1e29f) atomicMin(&binmin[cB0], __float_as_uint(dnB[0]));
        if (dnB[1] < 1e29f) atomicMin(&binmin[cB1], __float_as_uint(dnB[1]));
        if (dnB[2] < 1e29f) atomicMin(&binmin[cB2], __float_as_uint(dnB[2]));
        if (dnB[3] < 1e29f) atomicMin(&binmin[cB3], __float_as_uint(dnB[3]));
    }
    __syncthreads();

    if (wave == 0) {
        float s = 0.f, n = 0.f;
        if (P > 0) {
            // suffix-min over bins 0..P (chunked shfl scan, high chunk first)
            int nb = P + 1;
            int nch = (nb + 63) >> 6;
            float carry = BIG_F;
            for (int ch = nch - 1; ch >= 0; --ch) {
                int idx = ch * 64 + lane;
                float v = (idx < nb) ? __uint_as_float(binmin[idx]) : BIG_F;
                #pragma unroll
                for (int off = 1; off < 64; off <<= 1)
                    v = fminf(v, __shfl_down(v, off));
                v = fminf(v, carry);
                if (idx < nb) sufmin[idx] = v;
                carry = __shfl(v, 0);
            }
            // query eval: m(q)=#{q'<=q}; cand = sufmin[m]
            for (int base = 0; base < P; base += 64) {
                int k = base + lane;
                if (k < P) {
                    float q = qlist[k];
                    int m = 0;
                    for (int j = 0; j < P; ++j) m += (qlist[j] <= q);
                    float cand = sufmin[m];
                    if (cand < 1e29f && cand < q + MARGIN_F) { s += q - cand + MARGIN_F; n += 1.f; }
                }
            }
            #pragma unroll
            for (int off = 32; off > 0; off >>= 1) {
                s += __shfl_down(s, off);
                n += __shfl_down(n, off);
            }
        }
        if (lane == 0) {
            float hpAll = hpw[0], hnAll = hnw[0];
            #pragma unroll
            for (int w = 1; w < 8; ++w) { hpAll = fmaxf(hpAll, hpw[w]); hnAll = fminf(hnAll, hnw[w]); }
            bool valid = (P > 0 && hnAll < 1e29f);
            pb4[i * 4 + 0] = valid ? fmaxf(hpAll - hnAll + MARGIN_F, 0.f) : 0.f;
            pb4[i * 4 + 1] = valid ? 1.f : 0.f;
            pb4[i * 4 + 2] = s;
            pb4[i * 4 + 3] = n;
        }
    }
}

// ---------------- 5: finalize: partial sums + counts + intra/inter + combine ----------------
__global__ __launch_bounds__(256) void finalize_kernel(
        const float* __restrict__ T, const int* __restrict__ albl, const int* __restrict__ nlbl,
        const float* __restrict__ pbT, const float* __restrict__ pb4, float* __restrict__ out) {
    __shared__ int counts[NCLS];
    __shared__ int inA[NCLS];
    __shared__ float sred[256];
    int tid = threadIdx.x;
    if (tid < NCLS) { counts[tid] = 0; inA[tid] = 0; }
    __syncthreads();
    float tsum = 0.f, hsum = 0.f, hcnt = 0.f, ssum = 0.f, scnt = 0.f;
    for (int i = tid; i < B_DIM; i += 256) {
        atomicAdd(&counts[albl[i]], 2);
        inA[albl[i]] = 1;
        atomicAdd(&counts[nlbl[i]], 1);
        tsum += pbT[i];
        f32x4 p = *(const f32x4*)&pb4[i * 4];
        hsum += p[0]; hcnt += p[1]; ssum += p[2]; scnt += p[3];
    }
    __syncthreads();
    float intra = 0.f;
    if (tid < NCLS) {
        int c = tid;
        float cnt = (float)counts[c];
        if (inA[c] && counts[c] > 1)
            intra = T[c * NCLS + c] / fmaxf(cnt * (cnt - 1.f), 1.f);
    }
    float inter = 0.f;
    for (int x = tid; x < NCLS * NCLS; x += 256) {
        int c1 = x >> 6, c2 = x & 63;
        if (c1 < c2 && inA[c1] && inA[c2]) {
            float pn = (float)counts[c1] * (float)counts[c2];
            if (pn > 0.f) inter += fmaxf(MARGIN_F - T[x] / fmaxf(pn, 1.f), 0.f);
        }
    }
    float tsumA = block_reduce_sum(tsum, sred);
    float hsumA = block_reduce_sum(hsum, sred);
    float hcntA = block_reduce_sum(hcnt, sred);
    float ssumA = block_reduce_sum(ssum, sred);
    float scntA = block_reduce_sum(scnt, sred);
    float intraAll = block_reduce_sum(intra, sred);
    float interAll = block_reduce_sum(inter, sred);
    if (tid == 0) {
        float trip = tsumA / (float)B_DIM;
        float hard = (hcntA > 0.f) ? hsumA / fmaxf(hcntA, 1.f) : 0.f;
        float sh   = (scntA > 0.f) ? ssumA / fmaxf(scntA, 1.f) : 0.f;
        out[0] = trip + hard + sh + 0.1f * intraAll + 0.1f * interAll;
    }
}

// ---------------- launch ----------------
extern "C" void kernel_launch(void* const* d_in, const int* in_sizes, int n_in,
                              void* d_out, int out_size, void* d_ws, size_t ws_size,
                              hipStream_t stream) {
    const float* A  = (const float*)d_in[0];
    const float* P  = (const float*)d_in[1];
    const float* Ng = (const float*)d_in[2];
    const int* albl = (const int*)d_in[3];
    const int* nlbl = (const int*)d_in[4];
    char* ws = (char*)d_ws;
    // workspace layout (bytes)
    __bf16* Eb   = (__bf16*)(ws);                     // 3072*2048*2 = 12,582,912
    float* G     = (float*)(ws + 12582912);           // 1024*3072*4 = 12,582,912 (rows 0..1023 only)
    float* norms = (float*)(ws + 25165824);           // 3072*4
    float* T     = (float*)(ws + 25178112);           // 64*64*4
    int*   lab   = (int*)(ws + 25194496);             // 3072*4
    float* pbT   = (float*)(ws + 25206784);           // 1024*4
    float* pb4   = (float*)(ws + 25210880);           // 1024*4*4
    float* out   = (float*)d_out;

    hipLaunchKernelGGL(zero_kernel, dim3(16), dim3(256), 0, stream, T, albl, nlbl, lab);
    hipLaunchKernelGGL(prep_kernel, dim3(B_DIM), dim3(256), 0, stream, A, P, Ng, Eb, norms, pbT);
    hipLaunchKernelGGL(gram_gemm, dim3(NB128 * (NB128 + 1) / 2), dim3(256), 0, stream, Eb, G, norms, lab, T);
    hipLaunchKernelGGL(mirror_kernel, dim3(28 * 4), dim3(256), 0, stream, G);
    hipLaunchKernelGGL(minev_kernel, dim3(B_DIM), dim3(512), 0, stream, G, norms, lab, pb4);
    hipLaunchKernelGGL(finalize_kernel, dim3(1), dim3(256), 0, stream, T, albl, nlbl, pbT, pb4, out);
}

// Round 11
// 203.332 us; speedup vs baseline: 1.3104x; 1.2226x over previous
//
#include <hip/hip_runtime.h>
#include <hip/hip_bf16.h>
#include <stdint.h>

#define D_DIM 2048
#define B_DIM 1024
#define N_TOT 3072
#define NCLS 64
#define NB128 (N_TOT / 128)   // 24 tiles per side
#define MARGIN_F 0.8f
#define BIG_F 1e30f

typedef float f32x4 __attribute__((ext_vector_type(4)));
typedef int   i32x4 __attribute__((ext_vector_type(4)));
typedef __bf16 bf16x8 __attribute__((ext_vector_type(8)));

// async global->LDS, 16B per lane (m97 staging pattern).
__device__ __forceinline__ void gld_lds16(const __bf16* g, __bf16* l) {
    __builtin_amdgcn_global_load_lds(
        (const __attribute__((address_space(1))) void*)g,
        (__attribute__((address_space(3))) void*)l,
        16, 0, 0);
}

// ---------------- reduction helpers ----------------
__device__ inline float block_reduce_sum(float v, float* sred) {
    int tid = threadIdx.x;
    sred[tid] = v; __syncthreads();
    for (int s = 128; s > 0; s >>= 1) {
        if (tid < s) sred[tid] = sred[tid] + sred[tid + s];
        __syncthreads();
    }
    float r = sred[0]; __syncthreads();
    return r;
}
__device__ inline float block_sum4(float v, float* tmp4, int lane, int wave) {
    #pragma unroll
    for (int off = 32; off > 0; off >>= 1) v += __shfl_down(v, off);
    __syncthreads();
    if (lane == 0) tmp4[wave] = v;
    __syncthreads();
    return tmp4[0] + tmp4[1] + tmp4[2] + tmp4[3];
}
__device__ inline float wave_max(float v) {
    #pragma unroll
    for (int off = 32; off > 0; off >>= 1) v = fmaxf(v, __shfl_xor(v, off));
    return v;
}
__device__ inline float wave_min(float v) {
    #pragma unroll
    for (int off = 32; off > 0; off >>= 1) v = fminf(v, __shfl_xor(v, off));
    return v;
}

__device__ inline int label_of(int j, const int* __restrict__ albl, const int* __restrict__ nlbl) {
    return (j < 2 * B_DIM) ? albl[j & (B_DIM - 1)] : nlbl[j - 2 * B_DIM];
}

__device__ inline float sq8(f32x4 a, f32x4 b) {
    return a[0]*a[0] + a[1]*a[1] + a[2]*a[2] + a[3]*a[3]
         + b[0]*b[0] + b[1]*b[1] + b[2]*b[2] + b[3]*b[3];
}
__device__ inline void st_bf8(__bf16* dst, f32x4 v0, f32x4 v1) {
    bf16x8 o;
    o[0] = (__bf16)v0[0]; o[1] = (__bf16)v0[1]; o[2] = (__bf16)v0[2]; o[3] = (__bf16)v0[3];
    o[4] = (__bf16)v1[0]; o[5] = (__bf16)v1[1]; o[6] = (__bf16)v1[2]; o[7] = (__bf16)v1[3];
    *(bf16x8*)dst = o;
}

// ---------------- 0: zero T + pack labels ----------------
__global__ __launch_bounds__(256) void zero_kernel(
        float* __restrict__ T,
        const int* __restrict__ albl, const int* __restrict__ nlbl, int* __restrict__ lab) {
    int t = blockIdx.x * 256 + threadIdx.x;
    if (t < NCLS * NCLS) T[t] = 0.f;
    if (t < N_TOT) lab[t] = label_of(t, albl, nlbl);
}

// ---------------- 1: fused prep: bf16 convert + norms + triplet partial (no atomics) -----------
__global__ __launch_bounds__(256) void prep_kernel(
        const float* __restrict__ A, const float* __restrict__ P, const float* __restrict__ Ng,
        __bf16* __restrict__ Eb, float* __restrict__ norms, float* __restrict__ pbT) {
    __shared__ float tmp4[4];
    int i = blockIdx.x, tid = threadIdx.x;
    int lane = tid & 63, wave = tid >> 6;
    const f32x4* a4 = (const f32x4*)(A + (size_t)i * D_DIM);
    const f32x4* p4 = (const f32x4*)(P + (size_t)i * D_DIM);
    const f32x4* n4 = (const f32x4*)(Ng + (size_t)i * D_DIM);
    f32x4 av0 = a4[tid * 2], av1 = a4[tid * 2 + 1];
    f32x4 pv0 = p4[tid * 2], pv1 = p4[tid * 2 + 1];
    f32x4 nv0 = n4[tid * 2], nv1 = n4[tid * 2 + 1];
    float sa = sq8(av0, av1), sp = sq8(pv0, pv1), sn = sq8(nv0, nv1);
    f32x4 dp0 = av0 - pv0, dp1 = av1 - pv1;
    f32x4 dn0 = av0 - nv0, dn1 = av1 - nv1;
    float pd = sq8(dp0, dp1), nd = sq8(dn0, dn1);
    st_bf8(Eb + (size_t)i * D_DIM + tid * 8, av0, av1);
    st_bf8(Eb + (size_t)(B_DIM + i) * D_DIM + tid * 8, pv0, pv1);
    st_bf8(Eb + (size_t)(2 * B_DIM + i) * D_DIM + tid * 8, nv0, nv1);
    float saT = block_sum4(sa, tmp4, lane, wave);
    float spT = block_sum4(sp, tmp4, lane, wave);
    float snT = block_sum4(sn, tmp4, lane, wave);
    float pdT = block_sum4(pd, tmp4, lane, wave);
    float ndT = block_sum4(nd, tmp4, lane, wave);
    if (tid == 0) {
        norms[i] = saT;
        norms[B_DIM + i] = spT;
        norms[2 * B_DIM + i] = snT;
        pbT[i] = fmaxf(pdT - ndT + MARGIN_F, 0.f);
    }
}

// ---------------- 2: Gram (upper triangle) + fused T-binning, 8 waves, ordered-label bins ------
// R10 diagnosis: 300 blocks x 4 waves = 1.17 blocks/CU (occupancy 9.8%) -> barrier drain and
// epilogue fully exposed (MfmaUtil 5.7%); tb[rlb*64+cl] stride-64 atomics = 2.46M bank conflicts.
// Now: 512 threads (8 waves, 2x4 wave grid) ~9.4 waves/CU; T accumulated ONLY in ordered
// (min,max) label cells (T symmetric) -> 1 atomic per element; tb padded to stride 65.
__global__ __launch_bounds__(512) void gram_gemm(
        const __bf16* __restrict__ Eb, float* __restrict__ G,
        const float* __restrict__ norms, const int* __restrict__ lab, float* __restrict__ T) {
    __shared__ __bf16 As[128 * 32] __attribute__((aligned(16)));
    __shared__ __bf16 Bs[128 * 32] __attribute__((aligned(16)));
    __shared__ float tb[NCLS * 65];
    __shared__ float rnorm[128], cnorm[128];
    __shared__ int rlabs[128], clabs[128];
    int tid = threadIdx.x, lane = tid & 63, wave = tid >> 6;
    int by = 0, rem = blockIdx.x;
    while (rem >= NB128 - by) { rem -= (NB128 - by); ++by; }
    int bx = by + rem;
    size_t row0 = (size_t)by * 128, col0 = (size_t)bx * 128;
    int wr = wave >> 2, wc = wave & 3;          // 2x4 wave grid: 64x32 output per wave
    f32x4 acc[4][2];
    #pragma unroll
    for (int m = 0; m < 4; ++m)
        #pragma unroll
        for (int n = 0; n < 2; ++n) acc[m][n] = (f32x4){0.f, 0.f, 0.f, 0.f};

    if (tid < 128) { rnorm[tid] = norms[row0 + tid]; rlabs[tid] = lab[row0 + tid]; }
    else if (tid < 256) { int t = tid - 128; cnorm[t] = norms[col0 + t]; clabs[t] = lab[col0 + t]; }
    for (int x = tid; x < NCLS * 65; x += 512) tb[x] = 0.f;

    int rl = lane & 15;
    int kg = (lane >> 4) * 8;
    // staging: wave w covers rows [w*16, w*16+16); lane covers row w*16+(lane>>2), col (lane&3)*8
    int srow = wave * 16 + (lane >> 2), scol = (lane & 3) * 8;
    const __bf16* gA = Eb + (row0 + srow) * D_DIM + scol;
    const __bf16* gB = Eb + (col0 + srow) * D_DIM + scol;
    __bf16* lA = &As[(wave * 16) * 32];
    __bf16* lB = &Bs[(wave * 16) * 32];

    for (int k0 = 0; k0 < D_DIM; k0 += 32) {
        __syncthreads();          // iter0: publish staging/tb-init; later: prev ds_reads done
        gld_lds16(gA + k0, lA);
        gld_lds16(gB + k0, lB);
        __syncthreads();
        bf16x8 af[4], bf[2];
        #pragma unroll
        for (int m = 0; m < 4; ++m)
            af[m] = *(const bf16x8*)&As[(wr * 64 + m * 16 + rl) * 32 + kg];
        #pragma unroll
        for (int n = 0; n < 2; ++n)
            bf[n] = *(const bf16x8*)&Bs[(wc * 32 + n * 16 + rl) * 32 + kg];
        #pragma unroll
        for (int m = 0; m < 4; ++m)
            #pragma unroll
            for (int n = 0; n < 2; ++n)
                acc[m][n] = __builtin_amdgcn_mfma_f32_16x16x32_bf16(af[m], bf[n], acc[m][n], 0, 0, 0);
    }
    // C/D layout (HW-verified): col = lane&15, row = (lane>>4)*4 + reg
    int rg = (lane >> 4) * 4;
    bool offdiag = (by != bx);
    bool writeG = (by < 8);
    #pragma unroll
    for (int m = 0; m < 4; ++m)
        #pragma unroll
        for (int n = 0; n < 2; ++n) {
            int lcol = wc * 32 + n * 16 + rl;
            float cn = cnorm[lcol];
            int b = clabs[lcol];
            #pragma unroll
            for (int r = 0; r < 4; ++r) {
                int lrow = wr * 64 + m * 16 + rg + r;
                float g = acc[m][n][r];
                float d = sqrtf(fmaxf(rnorm[lrow] + cn - 2.f * g, 1e-8f));
                int a = rlabs[lrow];
                // ordered-label binning: T is symmetric; only (min,max) cells are read.
                if (offdiag) {
                    // tile covers global (r,c) AND mirror (c,r): exactly one has ordered labels
                    if (a == b) atomicAdd(&tb[a * 65 + a], 2.f * d);
                    else { int lo = min(a, b), hi = max(a, b); atomicAdd(&tb[lo * 65 + hi], d); }
                } else {
                    if (a < b) atomicAdd(&tb[a * 65 + b], d);
                    else if (a == b) atomicAdd(&tb[a * 65 + a], d);
                    // a > b: contributes to a never-read cell; mirror element handles (b,a)
                }
                if (writeG) G[(row0 + lrow) * N_TOT + col0 + lcol] = g;
            }
        }
    __syncthreads();
    for (int x = tid; x < NCLS * NCLS; x += 512) {
        int c1 = x >> 6, c2 = x & 63;
        if (c1 <= c2) {
            float v = tb[c1 * 65 + c2];
            if (v != 0.f) atomicAdd(&T[x], v);
        }
    }
}

// ---------------- 3: mirror (only tiles feeding minev rows < 1024) ----------------
__global__ __launch_bounds__(256) void mirror_kernel(float* __restrict__ G) {
    __shared__ float s[64 * 65];
    int b = blockIdx.x;
    int p = b >> 2, q = b & 3;
    int bj = 0, rem = p;
    while (rem >= 7 - bj) { rem -= (7 - bj); ++bj; }
    int bi = bj + 1 + rem;
    int ti = bi * 2 + (q >> 1), tj = bj * 2 + (q & 1);
    int tid = threadIdx.x;
    int c = tid & 63, r4 = tid >> 6;
    const float* src = G + ((size_t)tj * 64) * N_TOT + (size_t)ti * 64;  // upper tile (tj,ti)
    float* dst = G + ((size_t)ti * 64) * N_TOT + (size_t)tj * 64;        // lower tile (ti,tj)
    #pragma unroll
    for (int rr = 0; rr < 16; ++rr) {
        int row = rr * 4 + r4;
        s[row * 65 + c] = src[(size_t)row * N_TOT + c];
    }
    __syncthreads();
    #pragma unroll
    for (int rr = 0; rr < 16; ++rr) {
        int row = rr * 4 + r4;
        dst[(size_t)row * N_TOT + c] = s[c * 65 + row];
    }
}

// ---------------- 4: mining + successor (count-bucket); per-block partial outputs ----------
__global__ __launch_bounds__(512) void minev_kernel(
        const float* __restrict__ G, const float* __restrict__ norms,
        const int* __restrict__ lab, float* __restrict__ pb4) {
    __shared__ float qlist[128];
    __shared__ unsigned binmin[130];
    __shared__ float sufmin[130];
    __shared__ float hpw[8], hnw[8];
    __shared__ int pcount;
    int i = blockIdx.x, tid = threadIdx.x;
    int lane = tid & 63, wave = tid >> 6;
    if (tid == 0) pcount = 0;
    if (tid < 130) binmin[tid] = 0x7F800000u;   // +inf
    __syncthreads();
    int la = lab[i];
    float ni = norms[i];
    const float* Grow = G + (size_t)i * N_TOT;
    float hp = -BIG_F, hn = BIG_F;

    f32x4 dnA, dnB;
    {   // group A: j = tid*4 (0..2047)
        int j = tid * 4;
        f32x4 g = *(const f32x4*)&Grow[j];
        f32x4 nj = *(const f32x4*)&norms[j];
        i32x4 lj = *(const i32x4*)&lab[j];
        f32x4 d2 = ni + nj - 2.f * g;
        float d0 = sqrtf(fmaxf(d2[0], 1e-8f));
        float d1 = sqrtf(fmaxf(d2[1], 1e-8f));
        float dd2 = sqrtf(fmaxf(d2[2], 1e-8f));
        float d3 = sqrtf(fmaxf(d2[3], 1e-8f));
        bool n0 = lj[0] != la, n1 = lj[1] != la, n2 = lj[2] != la, n3 = lj[3] != la;
        dnA = (f32x4){ n0 ? d0 : BIG_F, n1 ? d1 : BIG_F, n2 ? dd2 : BIG_F, n3 ? d3 : BIG_F };
        hn = fminf(hn, fminf(fminf(dnA[0], dnA[1]), fminf(dnA[2], dnA[3])));
        if (!n0 && j + 0 != i) { hp = fmaxf(hp, d0); int p = atomicAdd(&pcount, 1); if (p < 128) qlist[p] = d0; }
        if (!n1 && j + 1 != i) { hp = fmaxf(hp, d1); int p = atomicAdd(&pcount, 1); if (p < 128) qlist[p] = d1; }
        if (!n2 && j + 2 != i) { hp = fmaxf(hp, dd2); int p = atomicAdd(&pcount, 1); if (p < 128) qlist[p] = dd2; }
        if (!n3 && j + 3 != i) { hp = fmaxf(hp, d3); int p = atomicAdd(&pcount, 1); if (p < 128) qlist[p] = d3; }
    }
    if (tid < 256) {   // group B: j = 2048 + tid*4 (2048..3071)
        int j = 2048 + tid * 4;
        f32x4 g = *(const f32x4*)&Grow[j];
        f32x4 nj = *(const f32x4*)&norms[j];
        i32x4 lj = *(const i32x4*)&lab[j];
        f32x4 d2 = ni + nj - 2.f * g;
        float d0 = sqrtf(fmaxf(d2[0], 1e-8f));
        float d1 = sqrtf(fmaxf(d2[1], 1e-8f));
        float dd2 = sqrtf(fmaxf(d2[2], 1e-8f));
        float d3 = sqrtf(fmaxf(d2[3], 1e-8f));
        bool n0 = lj[0] != la, n1 = lj[1] != la, n2 = lj[2] != la, n3 = lj[3] != la;
        dnB = (f32x4){ n0 ? d0 : BIG_F, n1 ? d1 : BIG_F, n2 ? dd2 : BIG_F, n3 ? d3 : BIG_F };
        hn = fminf(hn, fminf(fminf(dnB[0], dnB[1]), fminf(dnB[2], dnB[3])));
        if (!n0 && j + 0 != i) { hp = fmaxf(hp, d0); int p = atomicAdd(&pcount, 1); if (p < 128) qlist[p] = d0; }
        if (!n1 && j + 1 != i) { hp = fmaxf(hp, d1); int p = atomicAdd(&pcount, 1); if (p < 128) qlist[p] = d1; }
        if (!n2 && j + 2 != i) { hp = fmaxf(hp, dd2); int p = atomicAdd(&pcount, 1); if (p < 128) qlist[p] = dd2; }
        if (!n3 && j + 3 != i) { hp = fmaxf(hp, d3); int p = atomicAdd(&pcount, 1); if (p < 128) qlist[p] = d3; }
    } else {
        dnB = (f32x4){BIG_F, BIG_F, BIG_F, BIG_F};
    }
    float hpw_ = wave_max(hp), hnw_ = wave_min(hn);
    if (lane == 0) { hpw[wave] = hpw_; hnw[wave] = hnw_; }
    __syncthreads();                     // publish qlist, pcount, hpw/hnw

    int P = min(pcount, 128);
    if (P > 0) {
        // count phase: cnt = #{queries < v} strict; atomicMin only for REAL values
        int cA0 = 0, cA1 = 0, cA2 = 0, cA3 = 0, cB0 = 0, cB1 = 0, cB2 = 0, cB3 = 0;
        for (int k = 0; k < P; ++k) {
            float qk = qlist[k];         // broadcast read
            cA0 += (qk < dnA[0]); cA1 += (qk < dnA[1]);
            cA2 += (qk < dnA[2]); cA3 += (qk < dnA[3]);
            cB0 += (qk < dnB[0]); cB1 += (qk < dnB[1]);
            cB2 += (qk < dnB[2]); cB3 += (qk < dnB[3]);
        }
        if (dnA[0] < 1e29f) atomicMin(&binmin[cA0], __float_as_uint(dnA[0]));
        if (dnA[1] < 1e29f) atomicMin(&binmin[cA1], __float_as_uint(dnA[1]));
        if (dnA[2] < 1e29f) atomicMin(&binmin[cA2], __float_as_uint(dnA[2]));
        if (dnA[3] < 1e29f) atomicMin(&binmin[cA3], __float_as_uint(dnA[3]));
        if (dnB[0] < 1e29f) atomicMin(&binmin[cB0], __float_as_uint(dnB[0]));
        if (dnB[1] < 1e29f) atomicMin(&binmin[cB1], __float_as_uint(dnB[1]));
        if (dnB[2] < 1e29f) atomicMin(&binmin[cB2], __float_as_uint(dnB[2]));
        if (dnB[3] < 1e29f) atomicMin(&binmin[cB3], __float_as_uint(dnB[3]));
    }
    __syncthreads();

    if (wave == 0) {
        float s = 0.f, n = 0.f;
        if (P > 0) {
            // suffix-min over bins 0..P (chunked shfl scan, high chunk first)
            int nb = P + 1;
            int nch = (nb + 63) >> 6;
            float carry = BIG_F;
            for (int ch = nch - 1; ch >= 0; --ch) {
                int idx = ch * 64 + lane;
                float v = (idx < nb) ? __uint_as_float(binmin[idx]) : BIG_F;
                #pragma unroll
                for (int off = 1; off < 64; off <<= 1)
                    v = fminf(v, __shfl_down(v, off));
                v = fminf(v, carry);
                if (idx < nb) sufmin[idx] = v;
                carry = __shfl(v, 0);
            }
            // query eval: m(q)=#{q'<=q}; cand = sufmin[m]
            for (int base = 0; base < P; base += 64) {
                int k = base + lane;
                if (k < P) {
                    float q = qlist[k];
                    int m = 0;
                    for (int j = 0; j < P; ++j) m += (qlist[j] <= q);
                    float cand = sufmin[m];
                    if (cand < 1e29f && cand < q + MARGIN_F) { s += q - cand + MARGIN_F; n += 1.f; }
                }
            }
            #pragma unroll
            for (int off = 32; off > 0; off >>= 1) {
                s += __shfl_down(s, off);
                n += __shfl_down(n, off);
            }
        }
        if (lane == 0) {
            float hpAll = hpw[0], hnAll = hnw[0];
            #pragma unroll
            for (int w = 1; w < 8; ++w) { hpAll = fmaxf(hpAll, hpw[w]); hnAll = fminf(hnAll, hnw[w]); }
            bool valid = (P > 0 && hnAll < 1e29f);
            pb4[i * 4 + 0] = valid ? fmaxf(hpAll - hnAll + MARGIN_F, 0.f) : 0.f;
            pb4[i * 4 + 1] = valid ? 1.f : 0.f;
            pb4[i * 4 + 2] = s;
            pb4[i * 4 + 3] = n;
        }
    }
}

// ---------------- 5: finalize: partial sums + counts + intra/inter + combine ----------------
__global__ __launch_bounds__(256) void finalize_kernel(
        const float* __restrict__ T, const int* __restrict__ albl, const int* __restrict__ nlbl,
        const float* __restrict__ pbT, const float* __restrict__ pb4, float* __restrict__ out) {
    __shared__ int counts[NCLS];
    __shared__ int inA[NCLS];
    __shared__ float sred[256];
    int tid = threadIdx.x;
    if (tid < NCLS) { counts[tid] = 0; inA[tid] = 0; }
    __syncthreads();
    float tsum = 0.f, hsum = 0.f, hcnt = 0.f, ssum = 0.f, scnt = 0.f;
    for (int i = tid; i < B_DIM; i += 256) {
        atomicAdd(&counts[albl[i]], 2);
        inA[albl[i]] = 1;
        atomicAdd(&counts[nlbl[i]], 1);
        tsum += pbT[i];
        f32x4 p = *(const f32x4*)&pb4[i * 4];
        hsum += p[0]; hcnt += p[1]; ssum += p[2]; scnt += p[3];
    }
    __syncthreads();
    float intra = 0.f;
    if (tid < NCLS) {
        int c = tid;
        float cnt = (float)counts[c];
        if (inA[c] && counts[c] > 1)
            intra = T[c * NCLS + c] / fmaxf(cnt * (cnt - 1.f), 1.f);
    }
    float inter = 0.f;
    for (int x = tid; x < NCLS * NCLS; x += 256) {
        int c1 = x >> 6, c2 = x & 63;
        if (c1 < c2 && inA[c1] && inA[c2]) {
            float pn = (float)counts[c1] * (float)counts[c2];
            if (pn > 0.f) inter += fmaxf(MARGIN_F - T[x] / fmaxf(pn, 1.f), 0.f);
        }
    }
    float tsumA = block_reduce_sum(tsum, sred);
    float hsumA = block_reduce_sum(hsum, sred);
    float hcntA = block_reduce_sum(hcnt, sred);
    float ssumA = block_reduce_sum(ssum, sred);
    float scntA = block_reduce_sum(scnt, sred);
    float intraAll = block_reduce_sum(intra, sred);
    float interAll = block_reduce_sum(inter, sred);
    if (tid == 0) {
        float trip = tsumA / (float)B_DIM;
        float hard = (hcntA > 0.f) ? hsumA / fmaxf(hcntA, 1.f) : 0.f;
        float sh   = (scntA > 0.f) ? ssumA / fmaxf(scntA, 1.f) : 0.f;
        out[0] = trip + hard + sh + 0.1f * intraAll + 0.1f * interAll;
    }
}

// ---------------- launch ----------------
extern "C" void kernel_launch(void* const* d_in, const int* in_sizes, int n_in,
                              void* d_out, int out_size, void* d_ws, size_t ws_size,
                              hipStream_t stream) {
    const float* A  = (const float*)d_in[0];
    const float* P  = (const float*)d_in[1];
    const float* Ng = (const float*)d_in[2];
    const int* albl = (const int*)d_in[3];
    const int* nlbl = (const int*)d_in[4];
    char* ws = (char*)d_ws;
    // workspace layout (bytes)
    __bf16* Eb   = (__bf16*)(ws);                     // 3072*2048*2 = 12,582,912
    float* G     = (float*)(ws + 12582912);           // 1024*3072*4 = 12,582,912 (rows 0..1023 only)
    float* norms = (float*)(ws + 25165824);           // 3072*4
    float* T     = (float*)(ws + 25178112);           // 64*64*4
    int*   lab   = (int*)(ws + 25194496);             // 3072*4
    float* pbT   = (float*)(ws + 25206784);           // 1024*4
    float* pb4   = (float*)(ws + 25210880);           // 1024*4*4
    float* out   = (float*)d_out;

    hipLaunchKernelGGL(zero_kernel, dim3(16), dim3(256), 0, stream, T, albl, nlbl, lab);
    hipLaunchKernelGGL(prep_kernel, dim3(B_DIM), dim3(256), 0, stream, A, P, Ng, Eb, norms, pbT);
    hipLaunchKernelGGL(gram_gemm, dim3(NB128 * (NB128 + 1) / 2), dim3(512), 0, stream, Eb, G, norms, lab, T);
    hipLaunchKernelGGL(mirror_kernel, dim3(28 * 4), dim3(256), 0, stream, G);
    hipLaunchKernelGGL(minev_kernel, dim3(B_DIM), dim3(512), 0, stream, G, norms, lab, pb4);
    hipLaunchKernelGGL(finalize_kernel, dim3(1), dim3(256), 0, stream, T, albl, nlbl, pbT, pb4, out);
}

// Round 12
// 193.107 us; speedup vs baseline: 1.3798x; 1.0529x over previous
//
#include <hip/hip_runtime.h>
#include <hip/hip_bf16.h>
#include <stdint.h>

#define D_DIM 2048
#define B_DIM 1024
#define N_TOT 3072
#define NCLS 64
#define NB128 (N_TOT / 128)   // 24 tiles per side
#define MARGIN_F 0.8f
#define BIG_F 1e30f

typedef float f32x4 __attribute__((ext_vector_type(4)));
typedef int   i32x4 __attribute__((ext_vector_type(4)));
typedef __bf16 bf16x8 __attribute__((ext_vector_type(8)));

// async global->LDS, 16B per lane (m97 staging pattern).
__device__ __forceinline__ void gld_lds16(const __bf16* g, __bf16* l) {
    __builtin_amdgcn_global_load_lds(
        (const __attribute__((address_space(1))) void*)g,
        (__attribute__((address_space(3))) void*)l,
        16, 0, 0);
}

// ---------------- reduction helpers ----------------
__device__ inline float block_reduce_sum(float v, float* sred) {
    int tid = threadIdx.x;
    sred[tid] = v; __syncthreads();
    for (int s = 128; s > 0; s >>= 1) {
        if (tid < s) sred[tid] = sred[tid] + sred[tid + s];
        __syncthreads();
    }
    float r = sred[0]; __syncthreads();
    return r;
}
__device__ inline float block_sum4(float v, float* tmp4, int lane, int wave) {
    #pragma unroll
    for (int off = 32; off > 0; off >>= 1) v += __shfl_down(v, off);
    __syncthreads();
    if (lane == 0) tmp4[wave] = v;
    __syncthreads();
    return tmp4[0] + tmp4[1] + tmp4[2] + tmp4[3];
}
__device__ inline float wave_max(float v) {
    #pragma unroll
    for (int off = 32; off > 0; off >>= 1) v = fmaxf(v, __shfl_xor(v, off));
    return v;
}
__device__ inline float wave_min(float v) {
    #pragma unroll
    for (int off = 32; off > 0; off >>= 1) v = fminf(v, __shfl_xor(v, off));
    return v;
}

__device__ inline int label_of(int j, const int* __restrict__ albl, const int* __restrict__ nlbl) {
    return (j < 2 * B_DIM) ? albl[j & (B_DIM - 1)] : nlbl[j - 2 * B_DIM];
}

__device__ inline float sq8(f32x4 a, f32x4 b) {
    return a[0]*a[0] + a[1]*a[1] + a[2]*a[2] + a[3]*a[3]
         + b[0]*b[0] + b[1]*b[1] + b[2]*b[2] + b[3]*b[3];
}
__device__ inline void st_bf8(__bf16* dst, f32x4 v0, f32x4 v1) {
    bf16x8 o;
    o[0] = (__bf16)v0[0]; o[1] = (__bf16)v0[1]; o[2] = (__bf16)v0[2]; o[3] = (__bf16)v0[3];
    o[4] = (__bf16)v1[0]; o[5] = (__bf16)v1[1]; o[6] = (__bf16)v1[2]; o[7] = (__bf16)v1[3];
    *(bf16x8*)dst = o;
}

// ---------------- 0: zero T + pack labels ----------------
__global__ __launch_bounds__(256) void zero_kernel(
        float* __restrict__ T,
        const int* __restrict__ albl, const int* __restrict__ nlbl, int* __restrict__ lab) {
    int t = blockIdx.x * 256 + threadIdx.x;
    if (t < NCLS * NCLS) T[t] = 0.f;
    if (t < N_TOT) lab[t] = label_of(t, albl, nlbl);
}

// ---------------- 1: fused prep: bf16 convert + norms + triplet partial (no atomics) -----------
__global__ __launch_bounds__(256) void prep_kernel(
        const float* __restrict__ A, const float* __restrict__ P, const float* __restrict__ Ng,
        __bf16* __restrict__ Eb, float* __restrict__ norms, float* __restrict__ pbT) {
    __shared__ float tmp4[4];
    int i = blockIdx.x, tid = threadIdx.x;
    int lane = tid & 63, wave = tid >> 6;
    const f32x4* a4 = (const f32x4*)(A + (size_t)i * D_DIM);
    const f32x4* p4 = (const f32x4*)(P + (size_t)i * D_DIM);
    const f32x4* n4 = (const f32x4*)(Ng + (size_t)i * D_DIM);
    f32x4 av0 = a4[tid * 2], av1 = a4[tid * 2 + 1];
    f32x4 pv0 = p4[tid * 2], pv1 = p4[tid * 2 + 1];
    f32x4 nv0 = n4[tid * 2], nv1 = n4[tid * 2 + 1];
    float sa = sq8(av0, av1), sp = sq8(pv0, pv1), sn = sq8(nv0, nv1);
    f32x4 dp0 = av0 - pv0, dp1 = av1 - pv1;
    f32x4 dn0 = av0 - nv0, dn1 = av1 - nv1;
    float pd = sq8(dp0, dp1), nd = sq8(dn0, dn1);
    st_bf8(Eb + (size_t)i * D_DIM + tid * 8, av0, av1);
    st_bf8(Eb + (size_t)(B_DIM + i) * D_DIM + tid * 8, pv0, pv1);
    st_bf8(Eb + (size_t)(2 * B_DIM + i) * D_DIM + tid * 8, nv0, nv1);
    float saT = block_sum4(sa, tmp4, lane, wave);
    float spT = block_sum4(sp, tmp4, lane, wave);
    float snT = block_sum4(sn, tmp4, lane, wave);
    float pdT = block_sum4(pd, tmp4, lane, wave);
    float ndT = block_sum4(nd, tmp4, lane, wave);
    if (tid == 0) {
        norms[i] = saT;
        norms[B_DIM + i] = spT;
        norms[2 * B_DIM + i] = snT;
        pbT[i] = fmaxf(pdT - ndT + MARGIN_F, 0.f);
    }
}

// ---------------- 2: Gram (upper triangle), 2-phase pipelined, XOR-swizzled LDS --------------
// R11 diagnosis: 1.17 blocks/CU + stage->full-drain-barrier->compute = load latency fully
// exposed each K-step (MfmaUtil 8.7%); [128][32] LDS = 8-way conflict on b128 reads (3.69M).
// Now: BK=64 double-buffered; STAGE(next) issued BEFORE compute(cur); ONE barrier per K-step
// (32 vs 128). LDS rows are 128B = 8x16B slots, slot_col = logical_col ^ (row&7): ds_read
// becomes 2-way (free). global_load_lds writes linearly, so the SOURCE address is pre-swizzled
// (lanes still cover one contiguous 128B row -> coalescing preserved). tb overlays staging LDS.
__global__ __launch_bounds__(512) void gram_gemm(
        const __bf16* __restrict__ Eb, float* __restrict__ G,
        const float* __restrict__ norms, const int* __restrict__ lab, float* __restrict__ T) {
    __shared__ __align__(16) char smem[65536];   // 2 buffers x (A 16KB + B 16KB); tb overlay
    __shared__ float rnorm[128], cnorm[128];
    __shared__ int rlabs[128], clabs[128];
    int tid = threadIdx.x, lane = tid & 63, wave = tid >> 6;
    int by = 0, rem = blockIdx.x;
    while (rem >= NB128 - by) { rem -= (NB128 - by); ++by; }
    int bx = by + rem;
    size_t row0 = (size_t)by * 128, col0 = (size_t)bx * 128;
    int wr = wave >> 2, wc = wave & 3;          // 2x4 wave grid: 64x32 output per wave
    f32x4 acc[4][2];
    #pragma unroll
    for (int m = 0; m < 4; ++m)
        #pragma unroll
        for (int n = 0; n < 2; ++n) acc[m][n] = (f32x4){0.f, 0.f, 0.f, 0.f};

    if (tid < 128) { rnorm[tid] = norms[row0 + tid]; rlabs[tid] = lab[row0 + tid]; }
    else if (tid < 256) { int t = tid - 128; cnorm[t] = norms[col0 + t]; clabs[t] = lab[col0 + t]; }

    // staging geometry: wave w covers tile rows [w*16, w*16+16) for A and B.
    // gld covers 8 rows (64 lanes x 16B): lane l -> row +(l>>3), slot col (l&7).
    // slot col lc holds logical col (lc ^ (row&7)) -> fetch global col (lc ^ lr8).
    int lr8 = lane >> 3, lc = lane & 7;
    int gcol = (lc ^ lr8) * 8;                   // logical col in elements
    const __bf16* ga0 = Eb + (row0 + wave * 16 + lr8) * D_DIM + gcol;
    const __bf16* ga1 = ga0 + 8 * D_DIM;
    const __bf16* gb0 = Eb + (col0 + wave * 16 + lr8) * D_DIM + gcol;
    const __bf16* gb1 = gb0 + 8 * D_DIM;
    // LDS bases (elements): buffer b: A at b*16384, B at b*16384+8192 (in bf16 elems)
    __bf16* sm = (__bf16*)smem;

    const int nT = D_DIM / 64;                   // 32 K-steps
    // prologue: stage tile 0 into buf 0
    {
        __bf16* Ab = sm;            // buf0 A
        __bf16* Bb = sm + 8192;     // buf0 B
        gld_lds16(ga0, Ab + (wave * 16) * 64);
        gld_lds16(ga1, Ab + (wave * 16 + 8) * 64);
        gld_lds16(gb0, Bb + (wave * 16) * 64);
        gld_lds16(gb1, Bb + (wave * 16 + 8) * 64);
    }
    __syncthreads();

    int rl = lane & 15;
    int l7 = lane & 7;
    int cb0 = (lane >> 4);                       // logical 16B col for kk=0
    int cur = 0;
    for (int t = 0; t < nT; ++t) {
        // issue next tile's staging FIRST (overlaps with compute below)
        if (t + 1 < nT) {
            int k0 = (t + 1) * 64;
            __bf16* Ab = sm + (cur ^ 1) * 16384;
            __bf16* Bb = Ab + 8192;
            gld_lds16(ga0 + k0, Ab + (wave * 16) * 64);
            gld_lds16(ga1 + k0, Ab + (wave * 16 + 8) * 64);
            gld_lds16(gb0 + k0, Bb + (wave * 16) * 64);
            gld_lds16(gb1 + k0, Bb + (wave * 16 + 8) * 64);
        }
        // compute from current buffer
        __bf16* Ab = sm + cur * 16384;
        __bf16* Bb = Ab + 8192;
        #pragma unroll
        for (int kk = 0; kk < 2; ++kk) {
            int cb = cb0 + kk * 4;
            bf16x8 af[4], bf[2];
            #pragma unroll
            for (int m = 0; m < 4; ++m) {
                int r = wr * 64 + m * 16 + rl;
                af[m] = *(const bf16x8*)&Ab[r * 64 + (cb ^ l7) * 8];
            }
            #pragma unroll
            for (int n = 0; n < 2; ++n) {
                int r = wc * 32 + n * 16 + rl;
                bf[n] = *(const bf16x8*)&Bb[r * 64 + (cb ^ l7) * 8];
            }
            #pragma unroll
            for (int m = 0; m < 4; ++m)
                #pragma unroll
                for (int n = 0; n < 2; ++n)
                    acc[m][n] = __builtin_amdgcn_mfma_f32_16x16x32_bf16(af[m], bf[n], acc[m][n], 0, 0, 0);
        }
        __syncthreads();   // drains vmcnt (next tile staged) + lgkm (reads done)
        cur ^= 1;
    }

    // ---- epilogue: tb overlays the staging LDS (no longer needed) ----
    float* tb = (float*)smem;                    // NCLS*65 floats = 16.6KB < 32KB
    for (int x = tid; x < NCLS * 65; x += 512) tb[x] = 0.f;
    __syncthreads();
    // C/D layout (HW-verified): col = lane&15, row = (lane>>4)*4 + reg
    int rg = (lane >> 4) * 4;
    bool offdiag = (by != bx);
    bool writeG = (by < 8);
    #pragma unroll
    for (int m = 0; m < 4; ++m)
        #pragma unroll
        for (int n = 0; n < 2; ++n) {
            int lcol = wc * 32 + n * 16 + rl;
            float cn = cnorm[lcol];
            int b = clabs[lcol];
            #pragma unroll
            for (int r = 0; r < 4; ++r) {
                int lrow = wr * 64 + m * 16 + rg + r;
                float g = acc[m][n][r];
                float d = sqrtf(fmaxf(rnorm[lrow] + cn - 2.f * g, 1e-8f));
                int a = rlabs[lrow];
                // ordered-label binning: T symmetric; only (min,max) cells are read.
                if (offdiag) {
                    if (a == b) atomicAdd(&tb[a * 65 + a], 2.f * d);
                    else { int lo = min(a, b), hi = max(a, b); atomicAdd(&tb[lo * 65 + hi], d); }
                } else {
                    if (a < b) atomicAdd(&tb[a * 65 + b], d);
                    else if (a == b) atomicAdd(&tb[a * 65 + a], d);
                }
                if (writeG) G[(row0 + lrow) * N_TOT + col0 + lcol] = g;
            }
        }
    __syncthreads();
    for (int x = tid; x < NCLS * NCLS; x += 512) {
        int c1 = x >> 6, c2 = x & 63;
        if (c1 <= c2) {
            float v = tb[c1 * 65 + c2];
            if (v != 0.f) atomicAdd(&T[x], v);
        }
    }
}

// ---------------- 3: mirror (only tiles feeding minev rows < 1024) ----------------
__global__ __launch_bounds__(256) void mirror_kernel(float* __restrict__ G) {
    __shared__ float s[64 * 65];
    int b = blockIdx.x;
    int p = b >> 2, q = b & 3;
    int bj = 0, rem = p;
    while (rem >= 7 - bj) { rem -= (7 - bj); ++bj; }
    int bi = bj + 1 + rem;
    int ti = bi * 2 + (q >> 1), tj = bj * 2 + (q & 1);
    int tid = threadIdx.x;
    int c = tid & 63, r4 = tid >> 6;
    const float* src = G + ((size_t)tj * 64) * N_TOT + (size_t)ti * 64;  // upper tile (tj,ti)
    float* dst = G + ((size_t)ti * 64) * N_TOT + (size_t)tj * 64;        // lower tile (ti,tj)
    #pragma unroll
    for (int rr = 0; rr < 16; ++rr) {
        int row = rr * 4 + r4;
        s[row * 65 + c] = src[(size_t)row * N_TOT + c];
    }
    __syncthreads();
    #pragma unroll
    for (int rr = 0; rr < 16; ++rr) {
        int row = rr * 4 + r4;
        dst[(size_t)row * N_TOT + c] = s[c * 65 + row];
    }
}

// ---------------- 4: mining + successor (count-bucket); per-block partial outputs ----------
__global__ __launch_bounds__(512) void minev_kernel(
        const float* __restrict__ G, const float* __restrict__ norms,
        const int* __restrict__ lab, float* __restrict__ pb4) {
    __shared__ float qlist[128];
    __shared__ unsigned binmin[130];
    __shared__ float sufmin[130];
    __shared__ float hpw[8], hnw[8];
    __shared__ int pcount;
    int i = blockIdx.x, tid = threadIdx.x;
    int lane = tid & 63, wave = tid >> 6;
    if (tid == 0) pcount = 0;
    if (tid < 130) binmin[tid] = 0x7F800000u;   // +inf
    __syncthreads();
    int la = lab[i];
    float ni = norms[i];
    const float* Grow = G + (size_t)i * N_TOT;
    float hp = -BIG_F, hn = BIG_F;

    f32x4 dnA, dnB;
    {   // group A: j = tid*4 (0..2047)
        int j = tid * 4;
        f32x4 g = *(const f32x4*)&Grow[j];
        f32x4 nj = *(const f32x4*)&norms[j];
        i32x4 lj = *(const i32x4*)&lab[j];
        f32x4 d2 = ni + nj - 2.f * g;
        float d0 = sqrtf(fmaxf(d2[0], 1e-8f));
        float d1 = sqrtf(fmaxf(d2[1], 1e-8f));
        float dd2 = sqrtf(fmaxf(d2[2], 1e-8f));
        float d3 = sqrtf(fmaxf(d2[3], 1e-8f));
        bool n0 = lj[0] != la, n1 = lj[1] != la, n2 = lj[2] != la, n3 = lj[3] != la;
        dnA = (f32x4){ n0 ? d0 : BIG_F, n1 ? d1 : BIG_F, n2 ? dd2 : BIG_F, n3 ? d3 : BIG_F };
        hn = fminf(hn, fminf(fminf(dnA[0], dnA[1]), fminf(dnA[2], dnA[3])));
        if (!n0 && j + 0 != i) { hp = fmaxf(hp, d0); int p = atomicAdd(&pcount, 1); if (p < 128) qlist[p] = d0; }
        if (!n1 && j + 1 != i) { hp = fmaxf(hp, d1); int p = atomicAdd(&pcount, 1); if (p < 128) qlist[p] = d1; }
        if (!n2 && j + 2 != i) { hp = fmaxf(hp, dd2); int p = atomicAdd(&pcount, 1); if (p < 128) qlist[p] = dd2; }
        if (!n3 && j + 3 != i) { hp = fmaxf(hp, d3); int p = atomicAdd(&pcount, 1); if (p < 128) qlist[p] = d3; }
    }
    if (tid < 256) {   // group B: j = 2048 + tid*4 (2048..3071)
        int j = 2048 + tid * 4;
        f32x4 g = *(const f32x4*)&Grow[j];
        f32x4 nj = *(const f32x4*)&norms[j];
        i32x4 lj = *(const i32x4*)&lab[j];
        f32x4 d2 = ni + nj - 2.f * g;
        float d0 = sqrtf(fmaxf(d2[0], 1e-8f));
        float d1 = sqrtf(fmaxf(d2[1], 1e-8f));
        float dd2 = sqrtf(fmaxf(d2[2], 1e-8f));
        float d3 = sqrtf(fmaxf(d2[3], 1e-8f));
        bool n0 = lj[0] != la, n1 = lj[1] != la, n2 = lj[2] != la, n3 = lj[3] != la;
        dnB = (f32x4){ n0 ? d0 : BIG_F, n1 ? d1 : BIG_F, n2 ? dd2 : BIG_F, n3 ? d3 : BIG_F };
        hn = fminf(hn, fminf(fminf(dnB[0], dnB[1]), fminf(dnB[2], dnB[3])));
        if (!n0 && j + 0 != i) { hp = fmaxf(hp, d0); int p = atomicAdd(&pcount, 1); if (p < 128) qlist[p] = d0; }
        if (!n1 && j + 1 != i) { hp = fmaxf(hp, d1); int p = atomicAdd(&pcount, 1); if (p < 128) qlist[p] = d1; }
        if (!n2 && j + 2 != i) { hp = fmaxf(hp, dd2); int p = atomicAdd(&pcount, 1); if (p < 128) qlist[p] = dd2; }
        if (!n3 && j + 3 != i) { hp = fmaxf(hp, d3); int p = atomicAdd(&pcount, 1); if (p < 128) qlist[p] = d3; }
    } else {
        dnB = (f32x4){BIG_F, BIG_F, BIG_F, BIG_F};
    }
    float hpw_ = wave_max(hp), hnw_ = wave_min(hn);
    if (lane == 0) { hpw[wave] = hpw_; hnw[wave] = hnw_; }
    __syncthreads();                     // publish qlist, pcount, hpw/hnw

    int P = min(pcount, 128);
    if (P > 0) {
        // count phase: cnt = #{queries < v} strict; atomicMin only for REAL values
        int cA0 = 0, cA1 = 0, cA2 = 0, cA3 = 0, cB0 = 0, cB1 = 0, cB2 = 0, cB3 = 0;
        for (int k = 0; k < P; ++k) {
            float qk = qlist[k];         // broadcast read
            cA0 += (qk < dnA[0]); cA1 += (qk < dnA[1]);
            cA2 += (qk < dnA[2]); cA3 += (qk < dnA[3]);
            cB0 += (qk < dnB[0]); cB1 += (qk < dnB[1]);
            cB2 += (qk < dnB[2]); cB3 += (qk < dnB[3]);
        }
        if (dnA[0] < 1e29f) atomicMin(&binmin[cA0], __float_as_uint(dnA[0]));
        if (dnA[1] < 1e29f) atomicMin(&binmin[cA1], __float_as_uint(dnA[1]));
        if (dnA[2] < 1e29f) atomicMin(&binmin[cA2], __float_as_uint(dnA[2]));
        if (dnA[3] < 1e29f) atomicMin(&binmin[cA3], __float_as_uint(dnA[3]));
        if (dnB[0] < 1e29f) atomicMin(&binmin[cB0], __float_as_uint(dnB[0]));
        if (dnB[1] < 1e29f) atomicMin(&binmin[cB1], __float_as_uint(dnB[1]));
        if (dnB[2] < 1e29f) atomicMin(&binmin[cB2], __float_as_uint(dnB[2]));
        if (dnB[3] < 1e29f) atomicMin(&binmin[cB3], __float_as_uint(dnB[3]));
    }
    __syncthreads();

    if (wave == 0) {
        float s = 0.f, n = 0.f;
        if (P > 0) {
            // suffix-min over bins 0..P (chunked shfl scan, high chunk first)
            int nb = P + 1;
            int nch = (nb + 63) >> 6;
            float carry = BIG_F;
            for (int ch = nch - 1; ch >= 0; --ch) {
                int idx = ch * 64 + lane;
                float v = (idx < nb) ? __uint_as_float(binmin[idx]) : BIG_F;
                #pragma unroll
                for (int off = 1; off < 64; off <<= 1)
                    v = fminf(v, __shfl_down(v, off));
                v = fminf(v, carry);
                if (idx < nb) sufmin[idx] = v;
                carry = __shfl(v, 0);
            }
            // query eval: m(q)=#{q'<=q}; cand = sufmin[m]
            for (int base = 0; base < P; base += 64) {
                int k = base + lane;
                if (k < P) {
                    float q = qlist[k];
                    int m = 0;
                    for (int j = 0; j < P; ++j) m += (qlist[j] <= q);
                    float cand = sufmin[m];
                    if (cand < 1e29f && cand < q + MARGIN_F) { s += q - cand + MARGIN_F; n += 1.f; }
                }
            }
            #pragma unroll
            for (int off = 32; off > 0; off >>= 1) {
                s += __shfl_down(s, off);
                n += __shfl_down(n, off);
            }
        }
        if (lane == 0) {
            float hpAll = hpw[0], hnAll = hnw[0];
            #pragma unroll
            for (int w = 1; w < 8; ++w) { hpAll = fmaxf(hpAll, hpw[w]); hnAll = fminf(hnAll, hnw[w]); }
            bool valid = (P > 0 && hnAll < 1e29f);
            pb4[i * 4 + 0] = valid ? fmaxf(hpAll - hnAll + MARGIN_F, 0.f) : 0.f;
            pb4[i * 4 + 1] = valid ? 1.f : 0.f;
            pb4[i * 4 + 2] = s;
            pb4[i * 4 + 3] = n;
        }
    }
}

// ---------------- 5: finalize: partial sums + counts + intra/inter + combine ----------------
__global__ __launch_bounds__(256) void finalize_kernel(
        const float* __restrict__ T, const int* __restrict__ albl, const int* __restrict__ nlbl,
        const float* __restrict__ pbT, const float* __restrict__ pb4, float* __restrict__ out) {
    __shared__ int counts[NCLS];
    __shared__ int inA[NCLS];
    __shared__ float sred[256];
    int tid = threadIdx.x;
    if (tid < NCLS) { counts[tid] = 0; inA[tid] = 0; }
    __syncthreads();
    float tsum = 0.f, hsum = 0.f, hcnt = 0.f, ssum = 0.f, scnt = 0.f;
    for (int i = tid; i < B_DIM; i += 256) {
        atomicAdd(&counts[albl[i]], 2);
        inA[albl[i]] = 1;
        atomicAdd(&counts[nlbl[i]], 1);
        tsum += pbT[i];
        f32x4 p = *(const f32x4*)&pb4[i * 4];
        hsum += p[0]; hcnt += p[1]; ssum += p[2]; scnt += p[3];
    }
    __syncthreads();
    float intra = 0.f;
    if (tid < NCLS) {
        int c = tid;
        float cnt = (float)counts[c];
        if (inA[c] && counts[c] > 1)
            intra = T[c * NCLS + c] / fmaxf(cnt * (cnt - 1.f), 1.f);
    }
    float inter = 0.f;
    for (int x = tid; x < NCLS * NCLS; x += 256) {
        int c1 = x >> 6, c2 = x & 63;
        if (c1 < c2 && inA[c1] && inA[c2]) {
            float pn = (float)counts[c1] * (float)counts[c2];
            if (pn > 0.f) inter += fmaxf(MARGIN_F - T[x] / fmaxf(pn, 1.f), 0.f);
        }
    }
    float tsumA = block_reduce_sum(tsum, sred);
    float hsumA = block_reduce_sum(hsum, sred);
    float hcntA = block_reduce_sum(hcnt, sred);
    float ssumA = block_reduce_sum(ssum, sred);
    float scntA = block_reduce_sum(scnt, sred);
    float intraAll = block_reduce_sum(intra, sred);
    float interAll = block_reduce_sum(inter, sred);
    if (tid == 0) {
        float trip = tsumA / (float)B_DIM;
        float hard = (hcntA > 0.f) ? hsumA / fmaxf(hcntA, 1.f) : 0.f;
        float sh   = (scntA > 0.f) ? ssumA / fmaxf(scntA, 1.f) : 0.f;
        out[0] = trip + hard + sh + 0.1f * intraAll + 0.1f * interAll;
    }
}

// ---------------- launch ----------------
extern "C" void kernel_launch(void* const* d_in, const int* in_sizes, int n_in,
                              void* d_out, int out_size, void* d_ws, size_t ws_size,
                              hipStream_t stream) {
    const float* A  = (const float*)d_in[0];
    const float* P  = (const float*)d_in[1];
    const float* Ng = (const float*)d_in[2];
    const int* albl = (const int*)d_in[3];
    const int* nlbl = (const int*)d_in[4];
    char* ws = (char*)d_ws;
    // workspace layout (bytes)
    __bf16* Eb   = (__bf16*)(ws);                     // 3072*2048*2 = 12,582,912
    float* G     = (float*)(ws + 12582912);           // 1024*3072*4 = 12,582,912 (rows 0..1023 only)
    float* norms = (float*)(ws + 25165824);           // 3072*4
    float* T     = (float*)(ws + 25178112);           // 64*64*4
    int*   lab   = (int*)(ws + 25194496);             // 3072*4
    float* pbT   = (float*)(ws + 25206784);           // 1024*4
    float* pb4   = (float*)(ws + 25210880);           // 1024*4*4
    float* out   = (float*)d_out;

    hipLaunchKernelGGL(zero_kernel, dim3(16), dim3(256), 0, stream, T, albl, nlbl, lab);
    hipLaunchKernelGGL(prep_kernel, dim3(B_DIM), dim3(256), 0, stream, A, P, Ng, Eb, norms, pbT);
    hipLaunchKernelGGL(gram_gemm, dim3(NB128 * (NB128 + 1) / 2), dim3(512), 0, stream, Eb, G, norms, lab, T);
    hipLaunchKernelGGL(mirror_kernel, dim3(28 * 4), dim3(256), 0, stream, G);
    hipLaunchKernelGGL(minev_kernel, dim3(B_DIM), dim3(512), 0, stream, G, norms, lab, pb4);
    hipLaunchKernelGGL(finalize_kernel, dim3(1), dim3(256), 0, stream, T, albl, nlbl, pbT, pb4, out);
}